// Round 7
// baseline (426.256 us; speedup 1.0000x reference)
//
#include <hip/hip_runtime.h>
#include <math.h>

#define NNODES 50000
#define NEDGES 800000
#define DIN 128
#define D1 128          // HEADS*HID
#define HID 64
#define NEG_SLOPE 0.2f
#define SCAN_CHUNK 1024 // 256 threads x 4 elements
#define RPW 4           // gemm rows per wave

// ---------------- utility kernels ----------------

__global__ void k_zero_int(int* p, int n) {
    int i = blockIdx.x * blockDim.x + threadIdx.x;
    if (i < n) p[i] = 0;
}

// ---------------- CSR build ----------------

__global__ void k_count(const int* __restrict__ dst, int* __restrict__ counts, int e) {
    int i = blockIdx.x * blockDim.x + threadIdx.x;
    if (i < e) atomicAdd(&counts[dst[i]], 1);
}

// per-1024-chunk sums
__global__ __launch_bounds__(256) void k_partial(const int* __restrict__ c,
                                                 int* __restrict__ bsum, int n) {
    __shared__ int wsum[4];
    const int tid = threadIdx.x, lane = tid & 63, w = tid >> 6;
    int base = blockIdx.x * SCAN_CHUNK + tid * 4;
    int v = 0;
    if (base + 3 < n) {
        int4 x = *(const int4*)(c + base);
        v = x.x + x.y + x.z + x.w;
    } else {
        #pragma unroll
        for (int j = 0; j < 4; ++j) if (base + j < n) v += c[base + j];
    }
    #pragma unroll
    for (int o = 32; o > 0; o >>= 1) v += __shfl_xor(v, o, 64);
    if (lane == 0) wsum[w] = v;
    __syncthreads();
    if (tid == 0) bsum[blockIdx.x] = wsum[0] + wsum[1] + wsum[2] + wsum[3];
}

// single-block exclusive scan (used on the ~49 block sums)
__global__ void k_scan_excl(const int* __restrict__ counts, int* __restrict__ row_off, int n) {
    __shared__ int s_carry;
    __shared__ int s_wsum[4];
    const int tid  = threadIdx.x;
    const int lane = tid & 63;
    const int w    = tid >> 6;
    if (tid == 0) s_carry = 0;
    __syncthreads();
    for (int base = 0; base < n; base += 256) {
        int i = base + tid;
        int orig = (i < n) ? counts[i] : 0;
        int v = orig;
        #pragma unroll
        for (int o = 1; o < 64; o <<= 1) {
            int t = __shfl_up(v, o, 64);
            if (lane >= o) v += t;
        }
        if (lane == 63) s_wsum[w] = v;
        __syncthreads();
        int woff = 0;
        for (int j = 0; j < w; ++j) woff += s_wsum[j];
        int incl = v + woff;
        int carry = s_carry;
        if (i < n) row_off[i] = carry + incl - orig;
        __syncthreads();
        if (tid == 255) s_carry = carry + incl;
        __syncthreads();
    }
    if (tid == 0) row_off[n] = s_carry;
}

// per-chunk local exclusive scan + block offset; writes row_off AND cursor.
__global__ __launch_bounds__(256) void k_scan_chunk(const int* __restrict__ c,
                                                    const int* __restrict__ boff,
                                                    int* __restrict__ row_off,
                                                    int* __restrict__ cursor,
                                                    int n, int nb) {
    __shared__ int wsum[4];
    const int tid = threadIdx.x, lane = tid & 63, w = tid >> 6;
    int base = blockIdx.x * SCAN_CHUNK + tid * 4;
    int v0 = 0, v1 = 0, v2 = 0, v3 = 0;
    if (base + 3 < n) {
        int4 x = *(const int4*)(c + base);
        v0 = x.x; v1 = x.y; v2 = x.z; v3 = x.w;
    } else {
        if (base     < n) v0 = c[base];
        if (base + 1 < n) v1 = c[base + 1];
        if (base + 2 < n) v2 = c[base + 2];
        if (base + 3 < n) v3 = c[base + 3];
    }
    int ts = v0 + v1 + v2 + v3;
    int incl = ts;
    #pragma unroll
    for (int o = 1; o < 64; o <<= 1) {
        int t = __shfl_up(incl, o, 64);
        if (lane >= o) incl += t;
    }
    if (lane == 63) wsum[w] = incl;
    __syncthreads();
    int woff = 0;
    for (int j = 0; j < w; ++j) woff += wsum[j];
    int pre = boff[blockIdx.x] + woff + incl - ts;
    int e0 = pre, e1 = pre + v0, e2 = e1 + v1, e3 = e2 + v2;
    if (base     < n) { row_off[base]     = e0; cursor[base]     = e0; }
    if (base + 1 < n) { row_off[base + 1] = e1; cursor[base + 1] = e1; }
    if (base + 2 < n) { row_off[base + 2] = e2; cursor[base + 2] = e2; }
    if (base + 3 < n) { row_off[base + 3] = e3; cursor[base + 3] = e3; }
    if (blockIdx.x == 0 && tid == 0) row_off[n] = boff[nb];
}

__global__ void k_scatter(const int* __restrict__ src, const int* __restrict__ dst,
                          int* __restrict__ cursor, int* __restrict__ csr_src, int e) {
    int i = blockIdx.x * blockDim.x + threadIdx.x;
    if (i < e) {
        int d = dst[i];
        int slot = atomicAdd(&cursor[d], 1);
        csr_src[slot] = src[i];
    }
}

// ---------------- feat = h @ W ; el/er fused ----------------
// R3-proven geometry (empirical best: 81 us/dispatch): 256-thread blocks,
// __launch_bounds__(256) with NO min-wave clause, grid 1024, full W in LDS
// (64 KB), lane owns cols {2L,2L+1} (ds_read_b64), RPW=4 rows/wave.
// R4 lesson: launch_bounds ",4" caps VGPR -> spill. R5/R6 lesson: head-split
// and 512-thr blocks both regress; achieved occupancy is pinned ~18%
// regardless of geometry.
// FUSE (only change vs R3): layer-0 reads features + label_embed[label]
// inline — kills k_embed and the 25 MB h0 round-trip.

template<bool FUSE>
__global__ __launch_bounds__(256) void k_gemm_attn(
        const float* __restrict__ h,
        const float* __restrict__ features, const int* __restrict__ labels,
        const float* __restrict__ label_embed,
        const float* __restrict__ W,
        const float* __restrict__ al, const float* __restrict__ ar,
        float* __restrict__ feat, float* __restrict__ el, float* __restrict__ er, int n) {
    __shared__ float Ws[DIN * D1];      // 64 KB
    const int tid  = threadIdx.x;
    const int lane = tid & 63;
    const int w    = tid >> 6;
    for (int i = tid; i < DIN * D1 / 4; i += 256)
        ((float4*)Ws)[i] = ((const float4*)W)[i];
    __syncthreads();
    const float2* Ws2 = (const float2*)Ws;
    const int c0 = 2 * lane;
    const float al0 = al[c0], al1 = al[c0 + 1];
    const float ar0 = ar[c0], ar1 = ar[c0 + 1];

    const int groups = (n + RPW - 1) / RPW;
    for (int g = blockIdx.x * 4 + w; g < groups; g += gridDim.x * 4) {
        const int row0 = g * RPW;
        float2 acc[RPW];
        const float4* hp[RPW];
        const float4* lp[RPW];
        #pragma unroll
        for (int r = 0; r < RPW; ++r) {
            acc[r] = make_float2(0.f, 0.f);
            int rr = row0 + r; if (rr >= n) rr = n - 1;   // clamp (dup compute ok)
            if (FUSE) {
                hp[r] = (const float4*)(features + (size_t)rr * DIN);
                lp[r] = (const float4*)(label_embed + (size_t)labels[rr] * DIN);
            } else {
                hp[r] = (const float4*)(h + (size_t)rr * DIN);
            }
        }
        #pragma unroll 4
        for (int k4 = 0; k4 < DIN / 4; ++k4) {
            float2 w0 = Ws2[(4 * k4 + 0) * 64 + lane];
            float2 w1 = Ws2[(4 * k4 + 1) * 64 + lane];
            float2 w2 = Ws2[(4 * k4 + 2) * 64 + lane];
            float2 w3 = Ws2[(4 * k4 + 3) * 64 + lane];
            #pragma unroll
            for (int r = 0; r < RPW; ++r) {
                float4 a = hp[r][k4];
                if (FUSE) {
                    float4 le = lp[r][k4];
                    a.x += le.x; a.y += le.y; a.z += le.z; a.w += le.w;
                }
                acc[r].x = fmaf(a.x, w0.x, acc[r].x); acc[r].y = fmaf(a.x, w0.y, acc[r].y);
                acc[r].x = fmaf(a.y, w1.x, acc[r].x); acc[r].y = fmaf(a.y, w1.y, acc[r].y);
                acc[r].x = fmaf(a.z, w2.x, acc[r].x); acc[r].y = fmaf(a.z, w2.y, acc[r].y);
                acc[r].x = fmaf(a.w, w3.x, acc[r].x); acc[r].y = fmaf(a.w, w3.y, acc[r].y);
            }
        }
        #pragma unroll
        for (int r = 0; r < RPW; ++r) {
            int row = row0 + r;
            if (row >= n) break;
            float elv = acc[r].x * al0 + acc[r].y * al1;
            float erv = acc[r].x * ar0 + acc[r].y * ar1;
            #pragma unroll
            for (int o = 16; o > 0; o >>= 1) {
                elv += __shfl_xor(elv, o, 64);
                erv += __shfl_xor(erv, o, 64);
            }
            ((float2*)(feat + (size_t)row * D1))[lane] = acc[r];
            if (lane == 0)  { el[row * 2 + 0] = elv; er[row * 2 + 0] = erv; }
            if (lane == 32) { el[row * 2 + 1] = elv; er[row * 2 + 1] = erv; }
        }
    }
}

// ---------------- per-node aggregation (edge softmax + weighted sum) ----------------

__device__ __forceinline__ float leaky(float x) {
    return x > 0.f ? x : NEG_SLOPE * x;
}

__global__ __launch_bounds__(256) void k_node_agg(
        const float* __restrict__ feat, const float* __restrict__ el, const float* __restrict__ er,
        const int* __restrict__ row_off, const int* __restrict__ csr_src,
        const float* __restrict__ bias, float* __restrict__ out, int n) {
    const int wave = (blockIdx.x * blockDim.x + threadIdx.x) >> 6;
    const int lane = threadIdx.x & 63;
    if (wave >= n) return;
    const int node = wave;
    const int beg = row_off[node], end = row_off[node + 1];
    const int deg = end - beg;
    const float2 b2 = ((const float2*)bias)[lane];
    float2* outp = (float2*)(out + (size_t)node * D1);
    if (deg == 0) {
        outp[lane] = make_float2(fmaxf(b2.x, 0.f), fmaxf(b2.y, 0.f));
        return;
    }
    const float2 erv = ((const float2*)er)[node];
    float2 acc = make_float2(0.f, 0.f);

    if (deg <= 64) {
        int s_reg = 0;
        float e0 = -INFINITY, e1 = -INFINITY;
        if (lane < deg) {
            s_reg = csr_src[beg + lane];
            float2 elv = ((const float2*)el)[s_reg];
            e0 = leaky(elv.x + erv.x);
            e1 = leaky(elv.y + erv.y);
        }
        float m0 = e0, m1 = e1;
        #pragma unroll
        for (int o = 32; o > 0; o >>= 1) {
            m0 = fmaxf(m0, __shfl_xor(m0, o, 64));
            m1 = fmaxf(m1, __shfl_xor(m1, o, 64));
        }
        float p0 = (lane < deg) ? expf(e0 - m0) : 0.f;
        float p1 = (lane < deg) ? expf(e1 - m1) : 0.f;
        float s0 = p0, s1 = p1;
        #pragma unroll
        for (int o = 32; o > 0; o >>= 1) {
            s0 += __shfl_xor(s0, o, 64);
            s1 += __shfl_xor(s1, o, 64);
        }
        const float invh = (lane < 32) ? (1.f / s0) : (1.f / s1);
        for (int j = 0; j < deg; ++j) {
            int   sj  = __builtin_amdgcn_readlane(s_reg, j);
            float pj0 = __uint_as_float(__builtin_amdgcn_readlane(__float_as_uint(p0), j));
            float pj1 = __uint_as_float(__builtin_amdgcn_readlane(__float_as_uint(p1), j));
            float ah = ((lane < 32) ? pj0 : pj1) * invh;
            float2 f = ((const float2*)(feat + (size_t)sj * D1))[lane];
            acc.x = fmaf(ah, f.x, acc.x);
            acc.y = fmaf(ah, f.y, acc.y);
        }
    } else {
        float m0 = -INFINITY, m1 = -INFINITY;
        for (int j = beg + lane; j < end; j += 64) {
            int s = csr_src[j];
            float2 elv = ((const float2*)el)[s];
            m0 = fmaxf(m0, leaky(elv.x + erv.x));
            m1 = fmaxf(m1, leaky(elv.y + erv.y));
        }
        #pragma unroll
        for (int o = 32; o > 0; o >>= 1) {
            m0 = fmaxf(m0, __shfl_xor(m0, o, 64));
            m1 = fmaxf(m1, __shfl_xor(m1, o, 64));
        }
        float s0 = 0.f, s1 = 0.f;
        for (int j = beg + lane; j < end; j += 64) {
            int s = csr_src[j];
            float2 elv = ((const float2*)el)[s];
            s0 += expf(leaky(elv.x + erv.x) - m0);
            s1 += expf(leaky(elv.y + erv.y) - m1);
        }
        #pragma unroll
        for (int o = 32; o > 0; o >>= 1) {
            s0 += __shfl_xor(s0, o, 64);
            s1 += __shfl_xor(s1, o, 64);
        }
        const float inv0 = 1.f / s0, inv1 = 1.f / s1;
        for (int j = beg; j < end; ++j) {
            int s = csr_src[j];
            float2 elv = ((const float2*)el)[s];
            float a0 = expf(leaky(elv.x + erv.x) - m0) * inv0;
            float a1 = expf(leaky(elv.y + erv.y) - m1) * inv1;
            float ah = (lane < 32) ? a0 : a1;
            float2 f = ((const float2*)(feat + (size_t)s * D1))[lane];
            acc.x = fmaf(ah, f.x, acc.x);
            acc.y = fmaf(ah, f.y, acc.y);
        }
    }
    outp[lane] = make_float2(fmaxf(acc.x + b2.x, 0.f), fmaxf(acc.y + b2.y, 0.f));
}

// ---------------- launch ----------------

extern "C" void kernel_launch(void* const* d_in, const int* in_sizes, int n_in,
                              void* d_out, int out_size, void* d_ws, size_t ws_size,
                              hipStream_t stream) {
    const float* features    = (const float*)d_in[0];
    const int*   labels      = (const int*)  d_in[1];
    const int*   src         = (const int*)  d_in[2];
    const int*   dst         = (const int*)  d_in[3];
    const float* label_embed = (const float*)d_in[4];
    const float* W0  = (const float*)d_in[5];
    const float* al0 = (const float*)d_in[6];
    const float* ar0 = (const float*)d_in[7];
    const float* b0  = (const float*)d_in[8];
    const float* W1  = (const float*)d_in[9];
    const float* al1 = (const float*)d_in[10];
    const float* ar1 = (const float*)d_in[11];
    const float* b1  = (const float*)d_in[12];

    const int n = in_sizes[1];   // NNODES
    const int e = in_sizes[2];   // NEDGES
    const int nb = (n + SCAN_CHUNK - 1) / SCAN_CHUNK;

    size_t off = 0;
    auto carve = [&](size_t bytes) {
        void* p = (char*)d_ws + off;
        off += (bytes + 255) & ~(size_t)255;
        return p;
    };
    float* feat    = (float*)carve((size_t)n * D1 * 4);
    float* el      = (float*)carve((size_t)n * 2 * 4);
    float* er      = (float*)carve((size_t)n * 2 * 4);
    int*   row_off = (int*)  carve((size_t)(n + 1) * 4);
    int*   cursor  = (int*)  carve((size_t)n * 4);
    int*   csr_src = (int*)  carve((size_t)e * 4);
    int*   bsum    = (int*)  carve((size_t)nb * 4);
    int*   boff    = (int*)  carve((size_t)(nb + 1) * 4);
    float* h;
    if (off + (size_t)n * D1 * 4 <= ws_size)
        h = (float*)carve((size_t)n * D1 * 4);
    else
        h = (float*)d_out;

    const int B = 256;
    // --- CSR build ---
    hipLaunchKernelGGL(k_zero_int,  dim3((n + B - 1) / B), dim3(B), 0, stream, cursor, n);
    hipLaunchKernelGGL(k_count,     dim3((e + B - 1) / B), dim3(B), 0, stream, dst, cursor, e);
    hipLaunchKernelGGL(k_partial,   dim3(nb), dim3(B), 0, stream, cursor, bsum, n);
    hipLaunchKernelGGL(k_scan_excl, dim3(1),  dim3(B), 0, stream, bsum, boff, nb);
    hipLaunchKernelGGL(k_scan_chunk,dim3(nb), dim3(B), 0, stream, cursor, boff, row_off, cursor, n, nb);
    hipLaunchKernelGGL(k_scatter,   dim3((e + B - 1) / B), dim3(B), 0, stream, src, dst, cursor, csr_src, e);

    const int gemm_grid = 1024;   // R3-proven: 256-thr blocks, 2 resident/CU, dynamic refill
    const int agg_grid  = (n + 3) / 4;

    // --- layer 0 (embed fused into gemm) ---
    hipLaunchKernelGGL((k_gemm_attn<true>), dim3(gemm_grid), dim3(B), 0, stream,
                       (const float*)nullptr, features, labels, label_embed,
                       W0, al0, ar0, feat, el, er, n);
    hipLaunchKernelGGL(k_node_agg, dim3(agg_grid), dim3(B), 0, stream,
                       feat, el, er, row_off, csr_src, b0, h, n);

    // --- layer 1 ---
    hipLaunchKernelGGL((k_gemm_attn<false>), dim3(gemm_grid), dim3(B), 0, stream,
                       h, (const float*)nullptr, (const int*)nullptr, (const float*)nullptr,
                       W1, al1, ar1, feat, el, er, n);
    hipLaunchKernelGGL(k_node_agg, dim3(agg_grid), dim3(B), 0, stream,
                       feat, el, er, row_off, csr_src, b1, (float*)d_out, n);
}

// Round 8
// 351.259 us; speedup vs baseline: 1.2135x; 1.2135x over previous
//
#include <hip/hip_runtime.h>
#include <math.h>

#define NNODES 50000
#define NEDGES 800000
#define DIN 128
#define D1 128          // HEADS*HID
#define HID 64
#define NEG_SLOPE 0.2f
#define SCAN_CHUNK 1024 // 256 threads x 4 elements
#define KROWS 64        // K-rows staged per phase (32 KB LDS)
#define GR 8            // rows per wave
#define RPB 32          // rows per block (4 waves x GR)

// ---------------- utility kernels ----------------

__global__ void k_zero_int(int* p, int n) {
    int i = blockIdx.x * blockDim.x + threadIdx.x;
    if (i < n) p[i] = 0;
}

// ---------------- CSR build ----------------

__global__ void k_count(const int* __restrict__ dst, int* __restrict__ counts, int e) {
    int i = blockIdx.x * blockDim.x + threadIdx.x;
    if (i < e) atomicAdd(&counts[dst[i]], 1);
}

__global__ __launch_bounds__(256) void k_partial(const int* __restrict__ c,
                                                 int* __restrict__ bsum, int n) {
    __shared__ int wsum[4];
    const int tid = threadIdx.x, lane = tid & 63, w = tid >> 6;
    int base = blockIdx.x * SCAN_CHUNK + tid * 4;
    int v = 0;
    if (base + 3 < n) {
        int4 x = *(const int4*)(c + base);
        v = x.x + x.y + x.z + x.w;
    } else {
        #pragma unroll
        for (int j = 0; j < 4; ++j) if (base + j < n) v += c[base + j];
    }
    #pragma unroll
    for (int o = 32; o > 0; o >>= 1) v += __shfl_xor(v, o, 64);
    if (lane == 0) wsum[w] = v;
    __syncthreads();
    if (tid == 0) bsum[blockIdx.x] = wsum[0] + wsum[1] + wsum[2] + wsum[3];
}

__global__ void k_scan_excl(const int* __restrict__ counts, int* __restrict__ row_off, int n) {
    __shared__ int s_carry;
    __shared__ int s_wsum[4];
    const int tid  = threadIdx.x;
    const int lane = tid & 63;
    const int w    = tid >> 6;
    if (tid == 0) s_carry = 0;
    __syncthreads();
    for (int base = 0; base < n; base += 256) {
        int i = base + tid;
        int orig = (i < n) ? counts[i] : 0;
        int v = orig;
        #pragma unroll
        for (int o = 1; o < 64; o <<= 1) {
            int t = __shfl_up(v, o, 64);
            if (lane >= o) v += t;
        }
        if (lane == 63) s_wsum[w] = v;
        __syncthreads();
        int woff = 0;
        for (int j = 0; j < w; ++j) woff += s_wsum[j];
        int incl = v + woff;
        int carry = s_carry;
        if (i < n) row_off[i] = carry + incl - orig;
        __syncthreads();
        if (tid == 255) s_carry = carry + incl;
        __syncthreads();
    }
    if (tid == 0) row_off[n] = s_carry;
}

__global__ __launch_bounds__(256) void k_scan_chunk(const int* __restrict__ c,
                                                    const int* __restrict__ boff,
                                                    int* __restrict__ row_off,
                                                    int* __restrict__ cursor,
                                                    int n, int nb) {
    __shared__ int wsum[4];
    const int tid = threadIdx.x, lane = tid & 63, w = tid >> 6;
    int base = blockIdx.x * SCAN_CHUNK + tid * 4;
    int v0 = 0, v1 = 0, v2 = 0, v3 = 0;
    if (base + 3 < n) {
        int4 x = *(const int4*)(c + base);
        v0 = x.x; v1 = x.y; v2 = x.z; v3 = x.w;
    } else {
        if (base     < n) v0 = c[base];
        if (base + 1 < n) v1 = c[base + 1];
        if (base + 2 < n) v2 = c[base + 2];
        if (base + 3 < n) v3 = c[base + 3];
    }
    int ts = v0 + v1 + v2 + v3;
    int incl = ts;
    #pragma unroll
    for (int o = 1; o < 64; o <<= 1) {
        int t = __shfl_up(incl, o, 64);
        if (lane >= o) incl += t;
    }
    if (lane == 63) wsum[w] = incl;
    __syncthreads();
    int woff = 0;
    for (int j = 0; j < w; ++j) woff += wsum[j];
    int pre = boff[blockIdx.x] + woff + incl - ts;
    int e0 = pre, e1 = pre + v0, e2 = e1 + v1, e3 = e2 + v2;
    if (base     < n) { row_off[base]     = e0; cursor[base]     = e0; }
    if (base + 1 < n) { row_off[base + 1] = e1; cursor[base + 1] = e1; }
    if (base + 2 < n) { row_off[base + 2] = e2; cursor[base + 2] = e2; }
    if (base + 3 < n) { row_off[base + 3] = e3; cursor[base + 3] = e3; }
    if (blockIdx.x == 0 && tid == 0) row_off[n] = boff[nb];
}

__global__ void k_scatter(const int* __restrict__ src, const int* __restrict__ dst,
                          int* __restrict__ cursor, int* __restrict__ csr_src, int e) {
    int i = blockIdx.x * blockDim.x + threadIdx.x;
    if (i < e) {
        int d = dst[i];
        int slot = atomicAdd(&cursor[d], 1);
        csr_src[slot] = src[i];
    }
}

// ---------------- feat = h @ W ; el/er fused ----------------
// K-split double-phase: stage W[k-half][all 128 cols] (32 KB) per phase;
// accumulators persist across phases in registers. 32 KB LDS -> 5 blocks/CU
// (20 waves/CU theoretical vs 8 before — the ~19% occupancy cap was LDS).
// Each wave owns GR=8 fixed consecutive rows (acc = 16 VGPR); h addresses are
// wave-uniform (w readfirstlane'd, consecutive rows) -> scalar-path loads.
// Per k4-step: 4 ds_read_b64 feed 64 FMA (2x the FMA:ds ratio of the R3 loop).
// R4 lesson kept: no min-wave clause in launch_bounds (VGPR cap -> spill).

template<bool FUSE>
__global__ __launch_bounds__(256) void k_gemm_attn(
        const float* __restrict__ h,
        const float* __restrict__ features, const int* __restrict__ labels,
        const float* __restrict__ label_embed,
        const float* __restrict__ W,
        const float* __restrict__ al, const float* __restrict__ ar,
        float* __restrict__ feat, float* __restrict__ el, float* __restrict__ er, int n) {
    __shared__ float Ws[KROWS * D1];      // 32 KB
    const int tid  = threadIdx.x;
    const int lane = tid & 63;
    const int w    = __builtin_amdgcn_readfirstlane(tid >> 6);
    const float2* Ws2 = (const float2*)Ws;
    const int c0 = 2 * lane;
    const float al0 = al[c0], al1 = al[c0 + 1];
    const float ar0 = ar[c0], ar1 = ar[c0 + 1];

    const int row0 = blockIdx.x * RPB + w * GR;   // this wave's first row (uniform)

    // row base pointers (uniform -> SGPRs); clamp tail to n-1 (dup compute ok)
    const float* hb[GR];
    const float* lb[GR];
    #pragma unroll
    for (int r = 0; r < GR; ++r) {
        int rr = row0 + r; if (rr >= n) rr = n - 1;
        if (FUSE) {
            hb[r] = features + (size_t)rr * DIN;
            lb[r] = label_embed + (size_t)labels[rr] * DIN;
        } else {
            hb[r] = h + (size_t)rr * DIN;
        }
    }

    float2 acc[GR];
    #pragma unroll
    for (int r = 0; r < GR; ++r) acc[r] = make_float2(0.f, 0.f);

    for (int ph = 0; ph < 2; ++ph) {
        if (ph) __syncthreads();          // protect phase-0 reads before overwrite
        for (int i = tid; i < KROWS * D1 / 4; i += 256)
            ((float4*)Ws)[i] = ((const float4*)(W + ph * KROWS * D1))[i];
        __syncthreads();
        const int kb = ph * KROWS;        // global k offset of this phase
        #pragma unroll 4
        for (int k4 = 0; k4 < KROWS / 4; ++k4) {
            float2 w0 = Ws2[(4 * k4 + 0) * 64 + lane];
            float2 w1 = Ws2[(4 * k4 + 1) * 64 + lane];
            float2 w2 = Ws2[(4 * k4 + 2) * 64 + lane];
            float2 w3 = Ws2[(4 * k4 + 3) * 64 + lane];
            #pragma unroll
            for (int r = 0; r < GR; ++r) {
                float4 a = *(const float4*)(hb[r] + kb + 4 * k4);
                if (FUSE) {
                    float4 le = *(const float4*)(lb[r] + kb + 4 * k4);
                    a.x += le.x; a.y += le.y; a.z += le.z; a.w += le.w;
                }
                acc[r].x = fmaf(a.x, w0.x, acc[r].x); acc[r].y = fmaf(a.x, w0.y, acc[r].y);
                acc[r].x = fmaf(a.y, w1.x, acc[r].x); acc[r].y = fmaf(a.y, w1.y, acc[r].y);
                acc[r].x = fmaf(a.z, w2.x, acc[r].x); acc[r].y = fmaf(a.z, w2.y, acc[r].y);
                acc[r].x = fmaf(a.w, w3.x, acc[r].x); acc[r].y = fmaf(a.w, w3.y, acc[r].y);
            }
        }
    }

    #pragma unroll
    for (int r = 0; r < GR; ++r) {
        int row = row0 + r;
        if (row >= n) break;
        float elv = acc[r].x * al0 + acc[r].y * al1;
        float erv = acc[r].x * ar0 + acc[r].y * ar1;
        #pragma unroll
        for (int o = 16; o > 0; o >>= 1) {
            elv += __shfl_xor(elv, o, 64);
            erv += __shfl_xor(erv, o, 64);
        }
        ((float2*)(feat + (size_t)row * D1))[lane] = acc[r];
        if (lane == 0)  { el[row * 2 + 0] = elv; er[row * 2 + 0] = erv; }
        if (lane == 32) { el[row * 2 + 1] = elv; er[row * 2 + 1] = erv; }
    }
}

// ---------------- per-node aggregation (edge softmax + weighted sum) ----------------

__device__ __forceinline__ float leaky(float x) {
    return x > 0.f ? x : NEG_SLOPE * x;
}

__global__ __launch_bounds__(256) void k_node_agg(
        const float* __restrict__ feat, const float* __restrict__ el, const float* __restrict__ er,
        const int* __restrict__ row_off, const int* __restrict__ csr_src,
        const float* __restrict__ bias, float* __restrict__ out, int n) {
    const int wave = (blockIdx.x * blockDim.x + threadIdx.x) >> 6;
    const int lane = threadIdx.x & 63;
    if (wave >= n) return;
    const int node = wave;
    const int beg = row_off[node], end = row_off[node + 1];
    const int deg = end - beg;
    const float2 b2 = ((const float2*)bias)[lane];
    float2* outp = (float2*)(out + (size_t)node * D1);
    if (deg == 0) {
        outp[lane] = make_float2(fmaxf(b2.x, 0.f), fmaxf(b2.y, 0.f));
        return;
    }
    const float2 erv = ((const float2*)er)[node];
    float2 acc = make_float2(0.f, 0.f);

    if (deg <= 64) {
        int s_reg = 0;
        float e0 = -INFINITY, e1 = -INFINITY;
        if (lane < deg) {
            s_reg = csr_src[beg + lane];
            float2 elv = ((const float2*)el)[s_reg];
            e0 = leaky(elv.x + erv.x);
            e1 = leaky(elv.y + erv.y);
        }
        float m0 = e0, m1 = e1;
        #pragma unroll
        for (int o = 32; o > 0; o >>= 1) {
            m0 = fmaxf(m0, __shfl_xor(m0, o, 64));
            m1 = fmaxf(m1, __shfl_xor(m1, o, 64));
        }
        float p0 = (lane < deg) ? expf(e0 - m0) : 0.f;
        float p1 = (lane < deg) ? expf(e1 - m1) : 0.f;
        float s0 = p0, s1 = p1;
        #pragma unroll
        for (int o = 32; o > 0; o >>= 1) {
            s0 += __shfl_xor(s0, o, 64);
            s1 += __shfl_xor(s1, o, 64);
        }
        const float invh = (lane < 32) ? (1.f / s0) : (1.f / s1);
        for (int j = 0; j < deg; ++j) {
            int   sj  = __builtin_amdgcn_readlane(s_reg, j);
            float pj0 = __uint_as_float(__builtin_amdgcn_readlane(__float_as_uint(p0), j));
            float pj1 = __uint_as_float(__builtin_amdgcn_readlane(__float_as_uint(p1), j));
            float ah = ((lane < 32) ? pj0 : pj1) * invh;
            float2 f = ((const float2*)(feat + (size_t)sj * D1))[lane];
            acc.x = fmaf(ah, f.x, acc.x);
            acc.y = fmaf(ah, f.y, acc.y);
        }
    } else {
        float m0 = -INFINITY, m1 = -INFINITY;
        for (int j = beg + lane; j < end; j += 64) {
            int s = csr_src[j];
            float2 elv = ((const float2*)el)[s];
            m0 = fmaxf(m0, leaky(elv.x + erv.x));
            m1 = fmaxf(m1, leaky(elv.y + erv.y));
        }
        #pragma unroll
        for (int o = 32; o > 0; o >>= 1) {
            m0 = fmaxf(m0, __shfl_xor(m0, o, 64));
            m1 = fmaxf(m1, __shfl_xor(m1, o, 64));
        }
        float s0 = 0.f, s1 = 0.f;
        for (int j = beg + lane; j < end; j += 64) {
            int s = csr_src[j];
            float2 elv = ((const float2*)el)[s];
            s0 += expf(leaky(elv.x + erv.x) - m0);
            s1 += expf(leaky(elv.y + erv.y) - m1);
        }
        #pragma unroll
        for (int o = 32; o > 0; o >>= 1) {
            s0 += __shfl_xor(s0, o, 64);
            s1 += __shfl_xor(s1, o, 64);
        }
        const float inv0 = 1.f / s0, inv1 = 1.f / s1;
        for (int j = beg; j < end; ++j) {
            int s = csr_src[j];
            float2 elv = ((const float2*)el)[s];
            float a0 = expf(leaky(elv.x + erv.x) - m0) * inv0;
            float a1 = expf(leaky(elv.y + erv.y) - m1) * inv1;
            float ah = (lane < 32) ? a0 : a1;
            float2 f = ((const float2*)(feat + (size_t)s * D1))[lane];
            acc.x = fmaf(ah, f.x, acc.x);
            acc.y = fmaf(ah, f.y, acc.y);
        }
    }
    outp[lane] = make_float2(fmaxf(acc.x + b2.x, 0.f), fmaxf(acc.y + b2.y, 0.f));
}

// ---------------- launch ----------------

extern "C" void kernel_launch(void* const* d_in, const int* in_sizes, int n_in,
                              void* d_out, int out_size, void* d_ws, size_t ws_size,
                              hipStream_t stream) {
    const float* features    = (const float*)d_in[0];
    const int*   labels      = (const int*)  d_in[1];
    const int*   src         = (const int*)  d_in[2];
    const int*   dst         = (const int*)  d_in[3];
    const float* label_embed = (const float*)d_in[4];
    const float* W0  = (const float*)d_in[5];
    const float* al0 = (const float*)d_in[6];
    const float* ar0 = (const float*)d_in[7];
    const float* b0  = (const float*)d_in[8];
    const float* W1  = (const float*)d_in[9];
    const float* al1 = (const float*)d_in[10];
    const float* ar1 = (const float*)d_in[11];
    const float* b1  = (const float*)d_in[12];

    const int n = in_sizes[1];   // NNODES
    const int e = in_sizes[2];   // NEDGES
    const int nb = (n + SCAN_CHUNK - 1) / SCAN_CHUNK;

    size_t off = 0;
    auto carve = [&](size_t bytes) {
        void* p = (char*)d_ws + off;
        off += (bytes + 255) & ~(size_t)255;
        return p;
    };
    float* feat    = (float*)carve((size_t)n * D1 * 4);
    float* el      = (float*)carve((size_t)n * 2 * 4);
    float* er      = (float*)carve((size_t)n * 2 * 4);
    int*   row_off = (int*)  carve((size_t)(n + 1) * 4);
    int*   cursor  = (int*)  carve((size_t)n * 4);
    int*   csr_src = (int*)  carve((size_t)e * 4);
    int*   bsum    = (int*)  carve((size_t)nb * 4);
    int*   boff    = (int*)  carve((size_t)(nb + 1) * 4);
    float* h;
    if (off + (size_t)n * D1 * 4 <= ws_size)
        h = (float*)carve((size_t)n * D1 * 4);
    else
        h = (float*)d_out;

    const int B = 256;
    // --- CSR build ---
    hipLaunchKernelGGL(k_zero_int,  dim3((n + B - 1) / B), dim3(B), 0, stream, cursor, n);
    hipLaunchKernelGGL(k_count,     dim3((e + B - 1) / B), dim3(B), 0, stream, dst, cursor, e);
    hipLaunchKernelGGL(k_partial,   dim3(nb), dim3(B), 0, stream, cursor, bsum, n);
    hipLaunchKernelGGL(k_scan_excl, dim3(1),  dim3(B), 0, stream, bsum, boff, nb);
    hipLaunchKernelGGL(k_scan_chunk,dim3(nb), dim3(B), 0, stream, cursor, boff, row_off, cursor, n, nb);
    hipLaunchKernelGGL(k_scatter,   dim3((e + B - 1) / B), dim3(B), 0, stream, src, dst, cursor, csr_src, e);

    const int gemm_grid = (n + RPB - 1) / RPB;   // 1563 fixed-tile blocks
    const int agg_grid  = (n + 3) / 4;

    // --- layer 0 (embed fused into gemm) ---
    hipLaunchKernelGGL((k_gemm_attn<true>), dim3(gemm_grid), dim3(B), 0, stream,
                       (const float*)nullptr, features, labels, label_embed,
                       W0, al0, ar0, feat, el, er, n);
    hipLaunchKernelGGL(k_node_agg, dim3(agg_grid), dim3(B), 0, stream,
                       feat, el, er, row_off, csr_src, b0, h, n);

    // --- layer 1 ---
    hipLaunchKernelGGL((k_gemm_attn<false>), dim3(gemm_grid), dim3(B), 0, stream,
                       h, (const float*)nullptr, (const int*)nullptr, (const float*)nullptr,
                       W1, al1, ar1, feat, el, er, n);
    hipLaunchKernelGGL(k_node_agg, dim3(agg_grid), dim3(B), 0, stream,
                       feat, el, er, row_off, csr_src, b1, (float*)d_out, n);
}

// Round 9
// 289.754 us; speedup vs baseline: 1.4711x; 1.2123x over previous
//
#include <hip/hip_runtime.h>
#include <math.h>

#define NNODES 50000
#define NEDGES 800000
#define DIN 128
#define D1 128          // HEADS*HID
#define HID 64
#define NEG_SLOPE 0.2f
#define SCAN_CHUNK 1024

typedef __attribute__((ext_vector_type(4))) float f32x4;
typedef __attribute__((ext_vector_type(8))) short bf16x8;

// ---- bf16 split helpers (RNE) ----
__device__ __forceinline__ ushort f2bf(float x) {
    uint u = __float_as_uint(x);
    return (ushort)((u + 0x7fff + ((u >> 16) & 1)) >> 16);
}
__device__ __forceinline__ float bf2f(ushort h) {
    return __uint_as_float(((uint)h) << 16);
}
__device__ __forceinline__ void split2(float x, float y, uint& hi, uint& lo) {
    ushort xh = f2bf(x); ushort xl = f2bf(x - bf2f(xh));
    ushort yh = f2bf(y); ushort yl = f2bf(y - bf2f(yh));
    hi = (uint)xh | ((uint)yh << 16);
    lo = (uint)xl | ((uint)yl << 16);
}

// ---------------- utility ----------------

__global__ void k_zero_int(int* p, int n) {
    int i = blockIdx.x * blockDim.x + threadIdx.x;
    if (i < n) p[i] = 0;
}

// ---------------- CSR build ----------------

__global__ void k_count(const int* __restrict__ dst, int* __restrict__ counts, int e) {
    int i = blockIdx.x * blockDim.x + threadIdx.x;
    if (i < e) atomicAdd(&counts[dst[i]], 1);
}

__global__ __launch_bounds__(256) void k_partial(const int* __restrict__ c,
                                                 int* __restrict__ bsum, int n) {
    __shared__ int wsum[4];
    const int tid = threadIdx.x, lane = tid & 63, w = tid >> 6;
    int base = blockIdx.x * SCAN_CHUNK + tid * 4;
    int v = 0;
    if (base + 3 < n) {
        int4 x = *(const int4*)(c + base);
        v = x.x + x.y + x.z + x.w;
    } else {
        #pragma unroll
        for (int j = 0; j < 4; ++j) if (base + j < n) v += c[base + j];
    }
    #pragma unroll
    for (int o = 32; o > 0; o >>= 1) v += __shfl_xor(v, o, 64);
    if (lane == 0) wsum[w] = v;
    __syncthreads();
    if (tid == 0) bsum[blockIdx.x] = wsum[0] + wsum[1] + wsum[2] + wsum[3];
}

__global__ void k_scan_excl(const int* __restrict__ counts, int* __restrict__ row_off, int n) {
    __shared__ int s_carry;
    __shared__ int s_wsum[4];
    const int tid  = threadIdx.x;
    const int lane = tid & 63;
    const int w    = tid >> 6;
    if (tid == 0) s_carry = 0;
    __syncthreads();
    for (int base = 0; base < n; base += 256) {
        int i = base + tid;
        int orig = (i < n) ? counts[i] : 0;
        int v = orig;
        #pragma unroll
        for (int o = 1; o < 64; o <<= 1) {
            int t = __shfl_up(v, o, 64);
            if (lane >= o) v += t;
        }
        if (lane == 63) s_wsum[w] = v;
        __syncthreads();
        int woff = 0;
        for (int j = 0; j < w; ++j) woff += s_wsum[j];
        int incl = v + woff;
        int carry = s_carry;
        if (i < n) row_off[i] = carry + incl - orig;
        __syncthreads();
        if (tid == 255) s_carry = carry + incl;
        __syncthreads();
    }
    if (tid == 0) row_off[n] = s_carry;
}

__global__ __launch_bounds__(256) void k_scan_chunk(const int* __restrict__ c,
                                                    const int* __restrict__ boff,
                                                    int* __restrict__ row_off,
                                                    int* __restrict__ cursor,
                                                    int n, int nb) {
    __shared__ int wsum[4];
    const int tid = threadIdx.x, lane = tid & 63, w = tid >> 6;
    int base = blockIdx.x * SCAN_CHUNK + tid * 4;
    int v0 = 0, v1 = 0, v2 = 0, v3 = 0;
    if (base + 3 < n) {
        int4 x = *(const int4*)(c + base);
        v0 = x.x; v1 = x.y; v2 = x.z; v3 = x.w;
    } else {
        if (base     < n) v0 = c[base];
        if (base + 1 < n) v1 = c[base + 1];
        if (base + 2 < n) v2 = c[base + 2];
        if (base + 3 < n) v3 = c[base + 3];
    }
    int ts = v0 + v1 + v2 + v3;
    int incl = ts;
    #pragma unroll
    for (int o = 1; o < 64; o <<= 1) {
        int t = __shfl_up(incl, o, 64);
        if (lane >= o) incl += t;
    }
    if (lane == 63) wsum[w] = incl;
    __syncthreads();
    int woff = 0;
    for (int j = 0; j < w; ++j) woff += wsum[j];
    int pre = boff[blockIdx.x] + woff + incl - ts;
    int e0 = pre, e1 = pre + v0, e2 = e1 + v1, e3 = e2 + v2;
    if (base     < n) { row_off[base]     = e0; cursor[base]     = e0; }
    if (base + 1 < n) { row_off[base + 1] = e1; cursor[base + 1] = e1; }
    if (base + 2 < n) { row_off[base + 2] = e2; cursor[base + 2] = e2; }
    if (base + 3 < n) { row_off[base + 3] = e3; cursor[base + 3] = e3; }
    if (blockIdx.x == 0 && tid == 0) row_off[n] = boff[nb];
}

__global__ void k_scatter(const int* __restrict__ src, const int* __restrict__ dst,
                          int* __restrict__ cursor, int* __restrict__ csr_src, int e) {
    int i = blockIdx.x * blockDim.x + threadIdx.x;
    if (i < e) {
        int d = dst[i];
        int slot = atomicAdd(&cursor[d], 1);
        csr_src[slot] = src[i];
    }
}

// ---------------- pre-kernels for MFMA gemm ----------------

// h0 = features + label_embed[labels], split into bf16 hi/lo
__global__ void k_embed_split(const float* __restrict__ features, const int* __restrict__ labels,
                              const float* __restrict__ le,
                              ushort* __restrict__ h_hi, ushort* __restrict__ h_lo, int n) {
    int idx = blockIdx.x * blockDim.x + threadIdx.x;   // one float2 pair
    if (idx >= n * (DIN / 2)) return;
    int node = idx >> 6, q = idx & 63;
    float2 f = ((const float2*)features)[idx];
    float2 l = ((const float2*)(le + (size_t)labels[node] * DIN))[q];
    uint hi, lo;
    split2(f.x + l.x, f.y + l.y, hi, lo);
    ((uint*)h_hi)[idx] = hi;
    ((uint*)h_lo)[idx] = lo;
}

// W [128][128] f32 -> pre-swizzled bf16 hi/lo fragments.
// Slot order (must match gemm A-load): frag fi = ks*8+ct; lane l, elem j:
//   k = ks*32 + (l>>4)*8 + j, col = ct*16 + (l&15).
// Any bijective k-slot order is valid as long as A and B agree (k is a pure
// reduction index; HW pairs slots positionally). Only row(A)/col(B) = lane&15
// must match the C/D layout (col=lane&15, row=(lane>>4)*4+reg — m89-verified).
__global__ void k_wswz(const float* __restrict__ W,
                       ushort* __restrict__ swh, ushort* __restrict__ swl) {
    int t = blockIdx.x * blockDim.x + threadIdx.x;
    if (t >= 32 * 64) return;
    int fi = t >> 6, lane = t & 63;
    int ks = fi >> 3, ct = fi & 7;
    int kb = ks * 32 + ((lane >> 4) * 8);
    int col = ct * 16 + (lane & 15);
    uint h[4], l[4];
    #pragma unroll
    for (int p = 0; p < 4; ++p) {
        float v0 = W[(size_t)(kb + 2 * p) * D1 + col];
        float v1 = W[(size_t)(kb + 2 * p + 1) * D1 + col];
        split2(v0, v1, h[p], l[p]);
    }
    uint4* oh = (uint4*)(swh + fi * 512 + lane * 8);
    uint4* ol = (uint4*)(swl + fi * 512 + lane * 8);
    *oh = make_uint4(h[0], h[1], h[2], h[3]);
    *ol = make_uint4(l[0], l[1], l[2], l[3]);
}

// ---------------- MFMA gemm: feat = h @ W, el/er fused ----------------
// Split-bf16: C = Ah*Bh + Ah*Bl + Al*Bh (f32 acc). One wave per 16-row tile,
// full 128 cols (8 col-tiles of 16x16x32 mfma, 4 k-steps, 96 mfma/wave).
// No LDS, no barriers; B frags pre-swizzled in global (L2-hot).

__global__ __launch_bounds__(256) void k_gemm_mfma(
        const ushort* __restrict__ h_hi, const ushort* __restrict__ h_lo,
        const ushort* __restrict__ swh, const ushort* __restrict__ swl,
        const float* __restrict__ al, const float* __restrict__ ar,
        float* __restrict__ feat, float* __restrict__ el, float* __restrict__ er, int n) {
    const int lane = threadIdx.x & 63;
    const int w    = threadIdx.x >> 6;
    const int tile = blockIdx.x * 4 + w;
    if (tile * 16 >= n) return;
    const int row0 = tile * 16;
    const int arow = row0 + (lane & 15);
    const ushort* Ah_b = h_hi + (size_t)arow * DIN + ((lane >> 4) * 8);
    const ushort* Al_b = h_lo + (size_t)arow * DIN + ((lane >> 4) * 8);

    f32x4 acc[8];
    #pragma unroll
    for (int ct = 0; ct < 8; ++ct) acc[ct] = (f32x4){0.f, 0.f, 0.f, 0.f};

    #pragma unroll
    for (int ks = 0; ks < 4; ++ks) {
        bf16x8 Ah = *(const bf16x8*)(Ah_b + ks * 32);
        bf16x8 Al = *(const bf16x8*)(Al_b + ks * 32);
        #pragma unroll
        for (int ct = 0; ct < 8; ++ct) {
            const int fi = ks * 8 + ct;
            bf16x8 Bh = *(const bf16x8*)(swh + fi * 512 + lane * 8);
            bf16x8 Bl = *(const bf16x8*)(swl + fi * 512 + lane * 8);
            acc[ct] = __builtin_amdgcn_mfma_f32_16x16x32_bf16(Ah, Bh, acc[ct], 0, 0, 0);
            acc[ct] = __builtin_amdgcn_mfma_f32_16x16x32_bf16(Ah, Bl, acc[ct], 0, 0, 0);
            acc[ct] = __builtin_amdgcn_mfma_f32_16x16x32_bf16(Al, Bh, acc[ct], 0, 0, 0);
        }
    }

    // epilogue: C/D layout col = lane&15, row = (lane>>4)*4 + reg
    const int m0 = (lane >> 4) * 4;
    const int ncol = lane & 15;
    float elp0[4] = {0,0,0,0}, elp1[4] = {0,0,0,0};
    float erp0[4] = {0,0,0,0}, erp1[4] = {0,0,0,0};
    #pragma unroll
    for (int ct = 0; ct < 8; ++ct) {
        const float a_l = al[ct * 16 + ncol];
        const float a_r = ar[ct * 16 + ncol];
        #pragma unroll
        for (int r = 0; r < 4; ++r) {
            float v = acc[ct][r];
            feat[(size_t)(row0 + m0 + r) * D1 + ct * 16 + ncol] = v;
            if (ct < 4) { elp0[r] = fmaf(v, a_l, elp0[r]); erp0[r] = fmaf(v, a_r, erp0[r]); }
            else        { elp1[r] = fmaf(v, a_l, elp1[r]); erp1[r] = fmaf(v, a_r, erp1[r]); }
        }
    }
    #pragma unroll
    for (int o = 1; o < 16; o <<= 1) {
        #pragma unroll
        for (int r = 0; r < 4; ++r) {
            elp0[r] += __shfl_xor(elp0[r], o, 64);
            elp1[r] += __shfl_xor(elp1[r], o, 64);
            erp0[r] += __shfl_xor(erp0[r], o, 64);
            erp1[r] += __shfl_xor(erp1[r], o, 64);
        }
    }
    if (ncol == 0) {
        #pragma unroll
        for (int r = 0; r < 4; ++r) {
            int row = row0 + m0 + r;
            el[row * 2 + 0] = elp0[r]; el[row * 2 + 1] = elp1[r];
            er[row * 2 + 0] = erp0[r]; er[row * 2 + 1] = erp1[r];
        }
    }
}

// ---------------- per-node aggregation ----------------
// OUT_BF16: write result split into bf16 hi/lo (input of next gemm);
// else write f32 (final output).

__device__ __forceinline__ float leaky(float x) {
    return x > 0.f ? x : NEG_SLOPE * x;
}

template<bool OUT_BF16>
__global__ __launch_bounds__(256) void k_node_agg(
        const float* __restrict__ feat, const float* __restrict__ el, const float* __restrict__ er,
        const int* __restrict__ row_off, const int* __restrict__ csr_src,
        const float* __restrict__ bias,
        float* __restrict__ out, ushort* __restrict__ o_hi, ushort* __restrict__ o_lo, int n) {
    const int wave = (blockIdx.x * blockDim.x + threadIdx.x) >> 6;
    const int lane = threadIdx.x & 63;
    if (wave >= n) return;
    const int node = wave;
    const int beg = row_off[node], end = row_off[node + 1];
    const int deg = end - beg;
    const float2 b2 = ((const float2*)bias)[lane];
    const float2 erv = (deg > 0) ? ((const float2*)er)[node] : make_float2(0.f, 0.f);
    float2 acc = make_float2(0.f, 0.f);

    if (deg > 0 && deg <= 64) {
        int s_reg = 0;
        float e0 = -INFINITY, e1 = -INFINITY;
        if (lane < deg) {
            s_reg = csr_src[beg + lane];
            float2 elv = ((const float2*)el)[s_reg];
            e0 = leaky(elv.x + erv.x);
            e1 = leaky(elv.y + erv.y);
        }
        float m0 = e0, m1 = e1;
        #pragma unroll
        for (int o = 32; o > 0; o >>= 1) {
            m0 = fmaxf(m0, __shfl_xor(m0, o, 64));
            m1 = fmaxf(m1, __shfl_xor(m1, o, 64));
        }
        float p0 = (lane < deg) ? expf(e0 - m0) : 0.f;
        float p1 = (lane < deg) ? expf(e1 - m1) : 0.f;
        float s0 = p0, s1 = p1;
        #pragma unroll
        for (int o = 32; o > 0; o >>= 1) {
            s0 += __shfl_xor(s0, o, 64);
            s1 += __shfl_xor(s1, o, 64);
        }
        const float invh = (lane < 32) ? (1.f / s0) : (1.f / s1);
        for (int j = 0; j < deg; ++j) {
            int   sj  = __builtin_amdgcn_readlane(s_reg, j);
            float pj0 = __uint_as_float(__builtin_amdgcn_readlane(__float_as_uint(p0), j));
            float pj1 = __uint_as_float(__builtin_amdgcn_readlane(__float_as_uint(p1), j));
            float ah = ((lane < 32) ? pj0 : pj1) * invh;
            float2 f = ((const float2*)(feat + (size_t)sj * D1))[lane];
            acc.x = fmaf(ah, f.x, acc.x);
            acc.y = fmaf(ah, f.y, acc.y);
        }
    } else if (deg > 64) {
        float m0 = -INFINITY, m1 = -INFINITY;
        for (int j = beg + lane; j < end; j += 64) {
            int s = csr_src[j];
            float2 elv = ((const float2*)el)[s];
            m0 = fmaxf(m0, leaky(elv.x + erv.x));
            m1 = fmaxf(m1, leaky(elv.y + erv.y));
        }
        #pragma unroll
        for (int o = 32; o > 0; o >>= 1) {
            m0 = fmaxf(m0, __shfl_xor(m0, o, 64));
            m1 = fmaxf(m1, __shfl_xor(m1, o, 64));
        }
        float s0 = 0.f, s1 = 0.f;
        for (int j = beg + lane; j < end; j += 64) {
            int s = csr_src[j];
            float2 elv = ((const float2*)el)[s];
            s0 += expf(leaky(elv.x + erv.x) - m0);
            s1 += expf(leaky(elv.y + erv.y) - m1);
        }
        #pragma unroll
        for (int o = 32; o > 0; o >>= 1) {
            s0 += __shfl_xor(s0, o, 64);
            s1 += __shfl_xor(s1, o, 64);
        }
        const float inv0 = 1.f / s0, inv1 = 1.f / s1;
        for (int j = beg; j < end; ++j) {
            int s = csr_src[j];
            float2 elv = ((const float2*)el)[s];
            float a0 = expf(leaky(elv.x + erv.x) - m0) * inv0;
            float a1 = expf(leaky(elv.y + erv.y) - m1) * inv1;
            float ah = (lane < 32) ? a0 : a1;
            float2 f = ((const float2*)(feat + (size_t)s * D1))[lane];
            acc.x = fmaf(ah, f.x, acc.x);
            acc.y = fmaf(ah, f.y, acc.y);
        }
    }
    float o0 = fmaxf(acc.x + b2.x, 0.f);
    float o1 = fmaxf(acc.y + b2.y, 0.f);
    if (OUT_BF16) {
        uint hi, lo;
        split2(o0, o1, hi, lo);
        ((uint*)o_hi)[(size_t)node * (D1 / 2) + lane] = hi;
        ((uint*)o_lo)[(size_t)node * (D1 / 2) + lane] = lo;
    } else {
        ((float2*)(out + (size_t)node * D1))[lane] = make_float2(o0, o1);
    }
}

// ---------------- launch ----------------

extern "C" void kernel_launch(void* const* d_in, const int* in_sizes, int n_in,
                              void* d_out, int out_size, void* d_ws, size_t ws_size,
                              hipStream_t stream) {
    const float* features    = (const float*)d_in[0];
    const int*   labels      = (const int*)  d_in[1];
    const int*   src         = (const int*)  d_in[2];
    const int*   dst         = (const int*)  d_in[3];
    const float* label_embed = (const float*)d_in[4];
    const float* W0  = (const float*)d_in[5];
    const float* al0 = (const float*)d_in[6];
    const float* ar0 = (const float*)d_in[7];
    const float* b0  = (const float*)d_in[8];
    const float* W1  = (const float*)d_in[9];
    const float* al1 = (const float*)d_in[10];
    const float* ar1 = (const float*)d_in[11];
    const float* b1  = (const float*)d_in[12];

    const int n = in_sizes[1];   // NNODES
    const int e = in_sizes[2];   // NEDGES
    const int nb = (n + SCAN_CHUNK - 1) / SCAN_CHUNK;

    size_t off = 0;
    auto carve = [&](size_t bytes) {
        void* p = (char*)d_ws + off;
        off += (bytes + 255) & ~(size_t)255;
        return p;
    };
    float*  feat    = (float*) carve((size_t)n * D1 * 4);
    float*  el      = (float*) carve((size_t)n * 2 * 4);
    float*  er      = (float*) carve((size_t)n * 2 * 4);
    int*    row_off = (int*)   carve((size_t)(n + 1) * 4);
    int*    cursor  = (int*)   carve((size_t)n * 4);
    int*    csr_src = (int*)   carve((size_t)e * 4);
    int*    bsum    = (int*)   carve((size_t)nb * 4);
    int*    boff    = (int*)   carve((size_t)(nb + 1) * 4);
    ushort* w0h     = (ushort*)carve(32 * 512 * 2);
    ushort* w0l     = (ushort*)carve(32 * 512 * 2);
    ushort* w1h     = (ushort*)carve(32 * 512 * 2);
    ushort* w1l     = (ushort*)carve(32 * 512 * 2);
    ushort* h_hi;
    ushort* h_lo;
    if (off + 2 * (size_t)n * D1 * 2 <= ws_size) {
        h_hi = (ushort*)carve((size_t)n * D1 * 2);
        h_lo = (ushort*)carve((size_t)n * D1 * 2);
    } else {
        // d_out (25.6 MB f32) holds both bf16 halves; gemm1 reads them before
        // agg1 overwrites d_out with the final f32 result.
        h_hi = (ushort*)d_out;
        h_lo = h_hi + (size_t)n * D1;
    }

    const int B = 256;
    // --- CSR build ---
    hipLaunchKernelGGL(k_zero_int,  dim3((n + B - 1) / B), dim3(B), 0, stream, cursor, n);
    hipLaunchKernelGGL(k_count,     dim3((e + B - 1) / B), dim3(B), 0, stream, dst, cursor, e);
    hipLaunchKernelGGL(k_partial,   dim3(nb), dim3(B), 0, stream, cursor, bsum, n);
    hipLaunchKernelGGL(k_scan_excl, dim3(1),  dim3(B), 0, stream, bsum, boff, nb);
    hipLaunchKernelGGL(k_scan_chunk,dim3(nb), dim3(B), 0, stream, cursor, boff, row_off, cursor, n, nb);
    hipLaunchKernelGGL(k_scatter,   dim3((e + B - 1) / B), dim3(B), 0, stream, src, dst, cursor, csr_src, e);

    // --- W pre-swizzle + h0 split ---
    hipLaunchKernelGGL(k_wswz, dim3(8), dim3(B), 0, stream, W0, w0h, w0l);
    hipLaunchKernelGGL(k_wswz, dim3(8), dim3(B), 0, stream, W1, w1h, w1l);
    hipLaunchKernelGGL(k_embed_split, dim3((n * (DIN / 2) + B - 1) / B), dim3(B), 0, stream,
                       features, labels, label_embed, h_hi, h_lo, n);

    const int tiles = (n + 15) / 16;
    const int gemm_grid = (tiles + 3) / 4;
    const int agg_grid  = (n + 3) / 4;

    // --- layer 0 ---
    hipLaunchKernelGGL(k_gemm_mfma, dim3(gemm_grid), dim3(B), 0, stream,
                       h_hi, h_lo, w0h, w0l, al0, ar0, feat, el, er, n);
    hipLaunchKernelGGL((k_node_agg<true>), dim3(agg_grid), dim3(B), 0, stream,
                       feat, el, er, row_off, csr_src, b0,
                       (float*)nullptr, h_hi, h_lo, n);

    // --- layer 1 ---
    hipLaunchKernelGGL(k_gemm_mfma, dim3(gemm_grid), dim3(B), 0, stream,
                       h_hi, h_lo, w1h, w1l, al1, ar1, feat, el, er, n);
    hipLaunchKernelGGL((k_node_agg<false>), dim3(agg_grid), dim3(B), 0, stream,
                       feat, el, er, row_off, csr_src, b1,
                       (float*)d_out, (ushort*)nullptr, (ushort*)nullptr, n);
}

// Round 10
// 279.907 us; speedup vs baseline: 1.5228x; 1.0352x over previous
//
#include <hip/hip_runtime.h>
#include <hip/hip_fp16.h>
#include <math.h>

#define NNODES 50000
#define NEDGES 800000
#define DIN 128
#define D1 128          // HEADS*HID
#define HID 64
#define NEG_SLOPE 0.2f
#define SCAN_CHUNK 1024

typedef __attribute__((ext_vector_type(4))) float f32x4;
typedef __attribute__((ext_vector_type(8))) short bf16x8;

// ---- bf16 split helpers (RNE) ----
__device__ __forceinline__ ushort f2bf(float x) {
    uint u = __float_as_uint(x);
    return (ushort)((u + 0x7fff + ((u >> 16) & 1)) >> 16);
}
__device__ __forceinline__ float bf2f(ushort h) {
    return __uint_as_float(((uint)h) << 16);
}
__device__ __forceinline__ void split2(float x, float y, uint& hi, uint& lo) {
    ushort xh = f2bf(x); ushort xl = f2bf(x - bf2f(xh));
    ushort yh = f2bf(y); ushort yl = f2bf(y - bf2f(yh));
    hi = (uint)xh | ((uint)yh << 16);
    lo = (uint)xl | ((uint)yl << 16);
}

// ---------------- utility ----------------

__global__ void k_zero_int(int* p, int n) {
    int i = blockIdx.x * blockDim.x + threadIdx.x;
    if (i < n) p[i] = 0;
}

// ---------------- CSR build ----------------

__global__ void k_count(const int* __restrict__ dst, int* __restrict__ counts, int e) {
    int i = blockIdx.x * blockDim.x + threadIdx.x;
    if (i < e) atomicAdd(&counts[dst[i]], 1);
}

__global__ __launch_bounds__(256) void k_partial(const int* __restrict__ c,
                                                 int* __restrict__ bsum, int n) {
    __shared__ int wsum[4];
    const int tid = threadIdx.x, lane = tid & 63, w = tid >> 6;
    int base = blockIdx.x * SCAN_CHUNK + tid * 4;
    int v = 0;
    if (base + 3 < n) {
        int4 x = *(const int4*)(c + base);
        v = x.x + x.y + x.z + x.w;
    } else {
        #pragma unroll
        for (int j = 0; j < 4; ++j) if (base + j < n) v += c[base + j];
    }
    #pragma unroll
    for (int o = 32; o > 0; o >>= 1) v += __shfl_xor(v, o, 64);
    if (lane == 0) wsum[w] = v;
    __syncthreads();
    if (tid == 0) bsum[blockIdx.x] = wsum[0] + wsum[1] + wsum[2] + wsum[3];
}

__global__ void k_scan_excl(const int* __restrict__ counts, int* __restrict__ row_off, int n) {
    __shared__ int s_carry;
    __shared__ int s_wsum[4];
    const int tid  = threadIdx.x;
    const int lane = tid & 63;
    const int w    = tid >> 6;
    if (tid == 0) s_carry = 0;
    __syncthreads();
    for (int base = 0; base < n; base += 256) {
        int i = base + tid;
        int orig = (i < n) ? counts[i] : 0;
        int v = orig;
        #pragma unroll
        for (int o = 1; o < 64; o <<= 1) {
            int t = __shfl_up(v, o, 64);
            if (lane >= o) v += t;
        }
        if (lane == 63) s_wsum[w] = v;
        __syncthreads();
        int woff = 0;
        for (int j = 0; j < w; ++j) woff += s_wsum[j];
        int incl = v + woff;
        int carry = s_carry;
        if (i < n) row_off[i] = carry + incl - orig;
        __syncthreads();
        if (tid == 255) s_carry = carry + incl;
        __syncthreads();
    }
    if (tid == 0) row_off[n] = s_carry;
}

__global__ __launch_bounds__(256) void k_scan_chunk(const int* __restrict__ c,
                                                    const int* __restrict__ boff,
                                                    int* __restrict__ row_off,
                                                    int* __restrict__ cursor,
                                                    int n, int nb) {
    __shared__ int wsum[4];
    const int tid = threadIdx.x, lane = tid & 63, w = tid >> 6;
    int base = blockIdx.x * SCAN_CHUNK + tid * 4;
    int v0 = 0, v1 = 0, v2 = 0, v3 = 0;
    if (base + 3 < n) {
        int4 x = *(const int4*)(c + base);
        v0 = x.x; v1 = x.y; v2 = x.z; v3 = x.w;
    } else {
        if (base     < n) v0 = c[base];
        if (base + 1 < n) v1 = c[base + 1];
        if (base + 2 < n) v2 = c[base + 2];
        if (base + 3 < n) v3 = c[base + 3];
    }
    int ts = v0 + v1 + v2 + v3;
    int incl = ts;
    #pragma unroll
    for (int o = 1; o < 64; o <<= 1) {
        int t = __shfl_up(incl, o, 64);
        if (lane >= o) incl += t;
    }
    if (lane == 63) wsum[w] = incl;
    __syncthreads();
    int woff = 0;
    for (int j = 0; j < w; ++j) woff += wsum[j];
    int pre = boff[blockIdx.x] + woff + incl - ts;
    int e0 = pre, e1 = pre + v0, e2 = e1 + v1, e3 = e2 + v2;
    if (base     < n) { row_off[base]     = e0; cursor[base]     = e0; }
    if (base + 1 < n) { row_off[base + 1] = e1; cursor[base + 1] = e1; }
    if (base + 2 < n) { row_off[base + 2] = e2; cursor[base + 2] = e2; }
    if (base + 3 < n) { row_off[base + 3] = e3; cursor[base + 3] = e3; }
    if (blockIdx.x == 0 && tid == 0) row_off[n] = boff[nb];
}

__global__ void k_scatter(const int* __restrict__ src, const int* __restrict__ dst,
                          int* __restrict__ cursor, int* __restrict__ csr_src, int e) {
    int i = blockIdx.x * blockDim.x + threadIdx.x;
    if (i < e) {
        int d = dst[i];
        int slot = atomicAdd(&cursor[d], 1);
        csr_src[slot] = src[i];
    }
}

// ---------------- pre-kernels for MFMA gemm ----------------

// h0 = features + label_embed[labels], split into bf16 hi/lo
__global__ void k_embed_split(const float* __restrict__ features, const int* __restrict__ labels,
                              const float* __restrict__ le,
                              ushort* __restrict__ h_hi, ushort* __restrict__ h_lo, int n) {
    int idx = blockIdx.x * blockDim.x + threadIdx.x;   // one float2 pair
    if (idx >= n * (DIN / 2)) return;
    int node = idx >> 6, q = idx & 63;
    float2 f = ((const float2*)features)[idx];
    float2 l = ((const float2*)(le + (size_t)labels[node] * DIN))[q];
    uint hi, lo;
    split2(f.x + l.x, f.y + l.y, hi, lo);
    ((uint*)h_hi)[idx] = hi;
    ((uint*)h_lo)[idx] = lo;
}

// W [128][128] f32 -> pre-swizzled bf16 hi/lo fragments.
// Slot order (must match gemm A-load): frag fi = ks*8+ct; lane l, elem j:
//   k = ks*32 + (l>>4)*8 + j, col = ct*16 + (l&15).
// Any bijective k-slot order is valid as long as A and B agree (k is a pure
// reduction index; HW pairs slots positionally). Only row(A)/col(B) = lane&15
// must match the C/D layout (col=lane&15, row=(lane>>4)*4+reg — m89-verified).
__global__ void k_wswz(const float* __restrict__ W,
                       ushort* __restrict__ swh, ushort* __restrict__ swl) {
    int t = blockIdx.x * blockDim.x + threadIdx.x;
    if (t >= 32 * 64) return;
    int fi = t >> 6, lane = t & 63;
    int ks = fi >> 3, ct = fi & 7;
    int kb = ks * 32 + ((lane >> 4) * 8);
    int col = ct * 16 + (lane & 15);
    uint h[4], l[4];
    #pragma unroll
    for (int p = 0; p < 4; ++p) {
        float v0 = W[(size_t)(kb + 2 * p) * D1 + col];
        float v1 = W[(size_t)(kb + 2 * p + 1) * D1 + col];
        split2(v0, v1, h[p], l[p]);
    }
    uint4* oh = (uint4*)(swh + fi * 512 + lane * 8);
    uint4* ol = (uint4*)(swl + fi * 512 + lane * 8);
    *oh = make_uint4(h[0], h[1], h[2], h[3]);
    *ol = make_uint4(l[0], l[1], l[2], l[3]);
}

// ---------------- MFMA gemm: feat = h @ W, el/er fused ----------------
// Split-bf16: C = Ah*Bh + Ah*Bl + Al*Bh (f32 acc). One wave per 16-row tile,
// full 128 cols (8 col-tiles of 16x16x32 mfma, 4 k-steps, 96 mfma/wave).
// No LDS, no barriers; B frags pre-swizzled in global (L2-hot).
// feat is stored fp16 (R9 lesson: agg is gather-BW-bound; el/er keep full
// f32 precision since they're computed from the f32 accs here).

__global__ __launch_bounds__(256) void k_gemm_mfma(
        const ushort* __restrict__ h_hi, const ushort* __restrict__ h_lo,
        const ushort* __restrict__ swh, const ushort* __restrict__ swl,
        const float* __restrict__ al, const float* __restrict__ ar,
        __half* __restrict__ feat, float* __restrict__ el, float* __restrict__ er, int n) {
    const int lane = threadIdx.x & 63;
    const int w    = threadIdx.x >> 6;
    const int tile = blockIdx.x * 4 + w;
    if (tile * 16 >= n) return;
    const int row0 = tile * 16;
    const int arow = row0 + (lane & 15);
    const ushort* Ah_b = h_hi + (size_t)arow * DIN + ((lane >> 4) * 8);
    const ushort* Al_b = h_lo + (size_t)arow * DIN + ((lane >> 4) * 8);

    f32x4 acc[8];
    #pragma unroll
    for (int ct = 0; ct < 8; ++ct) acc[ct] = (f32x4){0.f, 0.f, 0.f, 0.f};

    #pragma unroll
    for (int ks = 0; ks < 4; ++ks) {
        bf16x8 Ah = *(const bf16x8*)(Ah_b + ks * 32);
        bf16x8 Al = *(const bf16x8*)(Al_b + ks * 32);
        #pragma unroll
        for (int ct = 0; ct < 8; ++ct) {
            const int fi = ks * 8 + ct;
            bf16x8 Bh = *(const bf16x8*)(swh + fi * 512 + lane * 8);
            bf16x8 Bl = *(const bf16x8*)(swl + fi * 512 + lane * 8);
            acc[ct] = __builtin_amdgcn_mfma_f32_16x16x32_bf16(Ah, Bh, acc[ct], 0, 0, 0);
            acc[ct] = __builtin_amdgcn_mfma_f32_16x16x32_bf16(Ah, Bl, acc[ct], 0, 0, 0);
            acc[ct] = __builtin_amdgcn_mfma_f32_16x16x32_bf16(Al, Bh, acc[ct], 0, 0, 0);
        }
    }

    // epilogue: C/D layout col = lane&15, row = (lane>>4)*4 + reg
    const int m0 = (lane >> 4) * 4;
    const int ncol = lane & 15;
    float elp0[4] = {0,0,0,0}, elp1[4] = {0,0,0,0};
    float erp0[4] = {0,0,0,0}, erp1[4] = {0,0,0,0};
    #pragma unroll
    for (int ct = 0; ct < 8; ++ct) {
        const float a_l = al[ct * 16 + ncol];
        const float a_r = ar[ct * 16 + ncol];
        #pragma unroll
        for (int r = 0; r < 4; ++r) {
            float v = acc[ct][r];
            feat[(size_t)(row0 + m0 + r) * D1 + ct * 16 + ncol] = __float2half(v);
            if (ct < 4) { elp0[r] = fmaf(v, a_l, elp0[r]); erp0[r] = fmaf(v, a_r, erp0[r]); }
            else        { elp1[r] = fmaf(v, a_l, elp1[r]); erp1[r] = fmaf(v, a_r, erp1[r]); }
        }
    }
    #pragma unroll
    for (int o = 1; o < 16; o <<= 1) {
        #pragma unroll
        for (int r = 0; r < 4; ++r) {
            elp0[r] += __shfl_xor(elp0[r], o, 64);
            elp1[r] += __shfl_xor(elp1[r], o, 64);
            erp0[r] += __shfl_xor(erp0[r], o, 64);
            erp1[r] += __shfl_xor(erp1[r], o, 64);
        }
    }
    if (ncol == 0) {
        #pragma unroll
        for (int r = 0; r < 4; ++r) {
            int row = row0 + m0 + r;
            el[row * 2 + 0] = elp0[r]; el[row * 2 + 1] = elp1[r];
            er[row * 2 + 0] = erp0[r]; er[row * 2 + 1] = erp1[r];
        }
    }
}

// ---------------- per-node aggregation ----------------
// Gather reads fp16 feat (half the bytes of R9's f32 — agg was gather-BW
// bound at FETCH=184MB). Accumulation stays f32.
// OUT_BF16: write result split into bf16 hi/lo (input of next gemm);
// else write f32 (final output).

__device__ __forceinline__ float leaky(float x) {
    return x > 0.f ? x : NEG_SLOPE * x;
}

template<bool OUT_BF16>
__global__ __launch_bounds__(256) void k_node_agg(
        const __half* __restrict__ feat, const float* __restrict__ el, const float* __restrict__ er,
        const int* __restrict__ row_off, const int* __restrict__ csr_src,
        const float* __restrict__ bias,
        float* __restrict__ out, ushort* __restrict__ o_hi, ushort* __restrict__ o_lo, int n) {
    const int wave = (blockIdx.x * blockDim.x + threadIdx.x) >> 6;
    const int lane = threadIdx.x & 63;
    if (wave >= n) return;
    const int node = wave;
    const int beg = row_off[node], end = row_off[node + 1];
    const int deg = end - beg;
    const float2 b2 = ((const float2*)bias)[lane];
    const float2 erv = (deg > 0) ? ((const float2*)er)[node] : make_float2(0.f, 0.f);
    float2 acc = make_float2(0.f, 0.f);

    if (deg > 0 && deg <= 64) {
        int s_reg = 0;
        float e0 = -INFINITY, e1 = -INFINITY;
        if (lane < deg) {
            s_reg = csr_src[beg + lane];
            float2 elv = ((const float2*)el)[s_reg];
            e0 = leaky(elv.x + erv.x);
            e1 = leaky(elv.y + erv.y);
        }
        float m0 = e0, m1 = e1;
        #pragma unroll
        for (int o = 32; o > 0; o >>= 1) {
            m0 = fmaxf(m0, __shfl_xor(m0, o, 64));
            m1 = fmaxf(m1, __shfl_xor(m1, o, 64));
        }
        float p0 = (lane < deg) ? expf(e0 - m0) : 0.f;
        float p1 = (lane < deg) ? expf(e1 - m1) : 0.f;
        float s0 = p0, s1 = p1;
        #pragma unroll
        for (int o = 32; o > 0; o >>= 1) {
            s0 += __shfl_xor(s0, o, 64);
            s1 += __shfl_xor(s1, o, 64);
        }
        const float invh = (lane < 32) ? (1.f / s0) : (1.f / s1);
        #pragma unroll 2
        for (int j = 0; j < deg; ++j) {
            int   sj  = __builtin_amdgcn_readlane(s_reg, j);
            float pj0 = __uint_as_float(__builtin_amdgcn_readlane(__float_as_uint(p0), j));
            float pj1 = __uint_as_float(__builtin_amdgcn_readlane(__float_as_uint(p1), j));
            float ah = ((lane < 32) ? pj0 : pj1) * invh;
            __half2 f = ((const __half2*)(feat + (size_t)sj * D1))[lane];
            acc.x = fmaf(ah, __low2float(f),  acc.x);
            acc.y = fmaf(ah, __high2float(f), acc.y);
        }
    } else if (deg > 64) {
        float m0 = -INFINITY, m1 = -INFINITY;
        for (int j = beg + lane; j < end; j += 64) {
            int s = csr_src[j];
            float2 elv = ((const float2*)el)[s];
            m0 = fmaxf(m0, leaky(elv.x + erv.x));
            m1 = fmaxf(m1, leaky(elv.y + erv.y));
        }
        #pragma unroll
        for (int o = 32; o > 0; o >>= 1) {
            m0 = fmaxf(m0, __shfl_xor(m0, o, 64));
            m1 = fmaxf(m1, __shfl_xor(m1, o, 64));
        }
        float s0 = 0.f, s1 = 0.f;
        for (int j = beg + lane; j < end; j += 64) {
            int s = csr_src[j];
            float2 elv = ((const float2*)el)[s];
            s0 += expf(leaky(elv.x + erv.x) - m0);
            s1 += expf(leaky(elv.y + erv.y) - m1);
        }
        #pragma unroll
        for (int o = 32; o > 0; o >>= 1) {
            s0 += __shfl_xor(s0, o, 64);
            s1 += __shfl_xor(s1, o, 64);
        }
        const float inv0 = 1.f / s0, inv1 = 1.f / s1;
        for (int j = beg; j < end; ++j) {
            int s = csr_src[j];
            float2 elv = ((const float2*)el)[s];
            float a0 = expf(leaky(elv.x + erv.x) - m0) * inv0;
            float a1 = expf(leaky(elv.y + erv.y) - m1) * inv1;
            float ah = (lane < 32) ? a0 : a1;
            __half2 f = ((const __half2*)(feat + (size_t)s * D1))[lane];
            acc.x = fmaf(ah, __low2float(f),  acc.x);
            acc.y = fmaf(ah, __high2float(f), acc.y);
        }
    }
    float o0 = fmaxf(acc.x + b2.x, 0.f);
    float o1 = fmaxf(acc.y + b2.y, 0.f);
    if (OUT_BF16) {
        uint hi, lo;
        split2(o0, o1, hi, lo);
        ((uint*)o_hi)[(size_t)node * (D1 / 2) + lane] = hi;
        ((uint*)o_lo)[(size_t)node * (D1 / 2) + lane] = lo;
    } else {
        ((float2*)(out + (size_t)node * D1))[lane] = make_float2(o0, o1);
    }
}

// ---------------- launch ----------------

extern "C" void kernel_launch(void* const* d_in, const int* in_sizes, int n_in,
                              void* d_out, int out_size, void* d_ws, size_t ws_size,
                              hipStream_t stream) {
    const float* features    = (const float*)d_in[0];
    const int*   labels      = (const int*)  d_in[1];
    const int*   src         = (const int*)  d_in[2];
    const int*   dst         = (const int*)  d_in[3];
    const float* label_embed = (const float*)d_in[4];
    const float* W0  = (const float*)d_in[5];
    const float* al0 = (const float*)d_in[6];
    const float* ar0 = (const float*)d_in[7];
    const float* b0  = (const float*)d_in[8];
    const float* W1  = (const float*)d_in[9];
    const float* al1 = (const float*)d_in[10];
    const float* ar1 = (const float*)d_in[11];
    const float* b1  = (const float*)d_in[12];

    const int n = in_sizes[1];   // NNODES
    const int e = in_sizes[2];   // NEDGES
    const int nb = (n + SCAN_CHUNK - 1) / SCAN_CHUNK;

    size_t off = 0;
    auto carve = [&](size_t bytes) {
        void* p = (char*)d_ws + off;
        off += (bytes + 255) & ~(size_t)255;
        return p;
    };
    __half* feat    = (__half*)carve((size_t)n * D1 * 2);
    float*  el      = (float*) carve((size_t)n * 2 * 4);
    float*  er      = (float*) carve((size_t)n * 2 * 4);
    int*    row_off = (int*)   carve((size_t)(n + 1) * 4);
    int*    cursor  = (int*)   carve((size_t)n * 4);
    int*    csr_src = (int*)   carve((size_t)e * 4);
    int*    bsum    = (int*)   carve((size_t)nb * 4);
    int*    boff    = (int*)   carve((size_t)(nb + 1) * 4);
    ushort* w0h     = (ushort*)carve(32 * 512 * 2);
    ushort* w0l     = (ushort*)carve(32 * 512 * 2);
    ushort* w1h     = (ushort*)carve(32 * 512 * 2);
    ushort* w1l     = (ushort*)carve(32 * 512 * 2);
    ushort* h_hi;
    ushort* h_lo;
    if (off + 2 * (size_t)n * D1 * 2 <= ws_size) {
        h_hi = (ushort*)carve((size_t)n * D1 * 2);
        h_lo = (ushort*)carve((size_t)n * D1 * 2);
    } else {
        // d_out (25.6 MB f32) holds both bf16 halves; gemm1 reads them before
        // agg1 overwrites d_out with the final f32 result.
        h_hi = (ushort*)d_out;
        h_lo = h_hi + (size_t)n * D1;
    }

    const int B = 256;
    // --- CSR build ---
    hipLaunchKernelGGL(k_zero_int,  dim3((n + B - 1) / B), dim3(B), 0, stream, cursor, n);
    hipLaunchKernelGGL(k_count,     dim3((e + B - 1) / B), dim3(B), 0, stream, dst, cursor, e);
    hipLaunchKernelGGL(k_partial,   dim3(nb), dim3(B), 0, stream, cursor, bsum, n);
    hipLaunchKernelGGL(k_scan_excl, dim3(1),  dim3(B), 0, stream, bsum, boff, nb);
    hipLaunchKernelGGL(k_scan_chunk,dim3(nb), dim3(B), 0, stream, cursor, boff, row_off, cursor, n, nb);
    hipLaunchKernelGGL(k_scatter,   dim3((e + B - 1) / B), dim3(B), 0, stream, src, dst, cursor, csr_src, e);

    // --- W pre-swizzle + h0 split ---
    hipLaunchKernelGGL(k_wswz, dim3(8), dim3(B), 0, stream, W0, w0h, w0l);
    hipLaunchKernelGGL(k_wswz, dim3(8), dim3(B), 0, stream, W1, w1h, w1l);
    hipLaunchKernelGGL(k_embed_split, dim3((n * (DIN / 2) + B - 1) / B), dim3(B), 0, stream,
                       features, labels, label_embed, h_hi, h_lo, n);

    const int tiles = (n + 15) / 16;
    const int gemm_grid = (tiles + 3) / 4;
    const int agg_grid  = (n + 3) / 4;

    // --- layer 0 ---
    hipLaunchKernelGGL(k_gemm_mfma, dim3(gemm_grid), dim3(B), 0, stream,
                       h_hi, h_lo, w0h, w0l, al0, ar0, feat, el, er, n);
    hipLaunchKernelGGL((k_node_agg<true>), dim3(agg_grid), dim3(B), 0, stream,
                       feat, el, er, row_off, csr_src, b0,
                       (float*)nullptr, h_hi, h_lo, n);

    // --- layer 1 ---
    hipLaunchKernelGGL(k_gemm_mfma, dim3(gemm_grid), dim3(B), 0, stream,
                       h_hi, h_lo, w1h, w1l, al1, ar1, feat, el, er, n);
    hipLaunchKernelGGL((k_node_agg<false>), dim3(agg_grid), dim3(B), 0, stream,
                       feat, el, er, row_off, csr_src, b1,
                       (float*)d_out, (ushort*)nullptr, (ushort*)nullptr, n);
}

// Round 11
// 237.959 us; speedup vs baseline: 1.7913x; 1.1763x over previous
//
#include <hip/hip_runtime.h>
#include <hip/hip_fp16.h>
#include <math.h>

#define NNODES 50000
#define NEDGES 800000
#define DIN 128
#define D1 128          // HEADS*HID
#define HID 64
#define NEG_SLOPE 0.2f
#define SCAN_CHUNK 1024

typedef __attribute__((ext_vector_type(4))) float f32x4;
typedef __attribute__((ext_vector_type(8))) short bf16x8;

// ---- bf16 split helpers (RNE) ----
__device__ __forceinline__ ushort f2bf(float x) {
    uint u = __float_as_uint(x);
    return (ushort)((u + 0x7fff + ((u >> 16) & 1)) >> 16);
}
__device__ __forceinline__ float bf2f(ushort h) {
    return __uint_as_float(((uint)h) << 16);
}
__device__ __forceinline__ void split2(float x, float y, uint& hi, uint& lo) {
    ushort xh = f2bf(x); ushort xl = f2bf(x - bf2f(xh));
    ushort yh = f2bf(y); ushort yl = f2bf(y - bf2f(yh));
    hi = (uint)xh | ((uint)yh << 16);
    lo = (uint)xl | ((uint)yl << 16);
}

// ---------------- utility ----------------

__global__ void k_zero_int(int* p, int n) {
    int i = blockIdx.x * blockDim.x + threadIdx.x;
    if (i < n) p[i] = 0;
}

// ---------------- CSR build ----------------

__global__ void k_count(const int* __restrict__ dst, int* __restrict__ counts, int e) {
    int i = blockIdx.x * blockDim.x + threadIdx.x;
    if (i < e) atomicAdd(&counts[dst[i]], 1);
}

__global__ __launch_bounds__(256) void k_partial(const int* __restrict__ c,
                                                 int* __restrict__ bsum, int n) {
    __shared__ int wsum[4];
    const int tid = threadIdx.x, lane = tid & 63, w = tid >> 6;
    int base = blockIdx.x * SCAN_CHUNK + tid * 4;
    int v = 0;
    if (base + 3 < n) {
        int4 x = *(const int4*)(c + base);
        v = x.x + x.y + x.z + x.w;
    } else {
        #pragma unroll
        for (int j = 0; j < 4; ++j) if (base + j < n) v += c[base + j];
    }
    #pragma unroll
    for (int o = 32; o > 0; o >>= 1) v += __shfl_xor(v, o, 64);
    if (lane == 0) wsum[w] = v;
    __syncthreads();
    if (tid == 0) bsum[blockIdx.x] = wsum[0] + wsum[1] + wsum[2] + wsum[3];
}

__global__ void k_scan_excl(const int* __restrict__ counts, int* __restrict__ row_off, int n) {
    __shared__ int s_carry;
    __shared__ int s_wsum[4];
    const int tid  = threadIdx.x;
    const int lane = tid & 63;
    const int w    = tid >> 6;
    if (tid == 0) s_carry = 0;
    __syncthreads();
    for (int base = 0; base < n; base += 256) {
        int i = base + tid;
        int orig = (i < n) ? counts[i] : 0;
        int v = orig;
        #pragma unroll
        for (int o = 1; o < 64; o <<= 1) {
            int t = __shfl_up(v, o, 64);
            if (lane >= o) v += t;
        }
        if (lane == 63) s_wsum[w] = v;
        __syncthreads();
        int woff = 0;
        for (int j = 0; j < w; ++j) woff += s_wsum[j];
        int incl = v + woff;
        int carry = s_carry;
        if (i < n) row_off[i] = carry + incl - orig;
        __syncthreads();
        if (tid == 255) s_carry = carry + incl;
        __syncthreads();
    }
    if (tid == 0) row_off[n] = s_carry;
}

__global__ __launch_bounds__(256) void k_scan_chunk(const int* __restrict__ c,
                                                    const int* __restrict__ boff,
                                                    int* __restrict__ row_off,
                                                    int* __restrict__ cursor,
                                                    int n, int nb) {
    __shared__ int wsum[4];
    const int tid = threadIdx.x, lane = tid & 63, w = tid >> 6;
    int base = blockIdx.x * SCAN_CHUNK + tid * 4;
    int v0 = 0, v1 = 0, v2 = 0, v3 = 0;
    if (base + 3 < n) {
        int4 x = *(const int4*)(c + base);
        v0 = x.x; v1 = x.y; v2 = x.z; v3 = x.w;
    } else {
        if (base     < n) v0 = c[base];
        if (base + 1 < n) v1 = c[base + 1];
        if (base + 2 < n) v2 = c[base + 2];
        if (base + 3 < n) v3 = c[base + 3];
    }
    int ts = v0 + v1 + v2 + v3;
    int incl = ts;
    #pragma unroll
    for (int o = 1; o < 64; o <<= 1) {
        int t = __shfl_up(incl, o, 64);
        if (lane >= o) incl += t;
    }
    if (lane == 63) wsum[w] = incl;
    __syncthreads();
    int woff = 0;
    for (int j = 0; j < w; ++j) woff += wsum[j];
    int pre = boff[blockIdx.x] + woff + incl - ts;
    int e0 = pre, e1 = pre + v0, e2 = e1 + v1, e3 = e2 + v2;
    if (base     < n) { row_off[base]     = e0; cursor[base]     = e0; }
    if (base + 1 < n) { row_off[base + 1] = e1; cursor[base + 1] = e1; }
    if (base + 2 < n) { row_off[base + 2] = e2; cursor[base + 2] = e2; }
    if (base + 3 < n) { row_off[base + 3] = e3; cursor[base + 3] = e3; }
    if (blockIdx.x == 0 && tid == 0) row_off[n] = boff[nb];
}

__global__ void k_scatter(const int* __restrict__ src, const int* __restrict__ dst,
                          int* __restrict__ cursor, int* __restrict__ csr_src, int e) {
    int i = blockIdx.x * blockDim.x + threadIdx.x;
    if (i < e) {
        int d = dst[i];
        int slot = atomicAdd(&cursor[d], 1);
        csr_src[slot] = src[i];
    }
}

// ---------------- pre-kernels for MFMA gemm ----------------

__global__ void k_embed_split(const float* __restrict__ features, const int* __restrict__ labels,
                              const float* __restrict__ le,
                              ushort* __restrict__ h_hi, ushort* __restrict__ h_lo, int n) {
    int idx = blockIdx.x * blockDim.x + threadIdx.x;   // one float2 pair
    if (idx >= n * (DIN / 2)) return;
    int node = idx >> 6, q = idx & 63;
    float2 f = ((const float2*)features)[idx];
    float2 l = ((const float2*)(le + (size_t)labels[node] * DIN))[q];
    uint hi, lo;
    split2(f.x + l.x, f.y + l.y, hi, lo);
    ((uint*)h_hi)[idx] = hi;
    ((uint*)h_lo)[idx] = lo;
}

// W [128][128] f32 -> pre-swizzled bf16 hi/lo fragments (see R9 notes: only
// row(A)/col(B)=lane&15 must match C/D layout; k-slot order just needs A/B agree).
__global__ void k_wswz(const float* __restrict__ W,
                       ushort* __restrict__ swh, ushort* __restrict__ swl) {
    int t = blockIdx.x * blockDim.x + threadIdx.x;
    if (t >= 32 * 64) return;
    int fi = t >> 6, lane = t & 63;
    int ks = fi >> 3, ct = fi & 7;
    int kb = ks * 32 + ((lane >> 4) * 8);
    int col = ct * 16 + (lane & 15);
    uint h[4], l[4];
    #pragma unroll
    for (int p = 0; p < 4; ++p) {
        float v0 = W[(size_t)(kb + 2 * p) * D1 + col];
        float v1 = W[(size_t)(kb + 2 * p + 1) * D1 + col];
        split2(v0, v1, h[p], l[p]);
    }
    uint4* oh = (uint4*)(swh + fi * 512 + lane * 8);
    uint4* ol = (uint4*)(swl + fi * 512 + lane * 8);
    *oh = make_uint4(h[0], h[1], h[2], h[3]);
    *ol = make_uint4(l[0], l[1], l[2], l[3]);
}

// ---------------- MFMA gemm: feat = h @ W, el/er fused ----------------

__global__ __launch_bounds__(256) void k_gemm_mfma(
        const ushort* __restrict__ h_hi, const ushort* __restrict__ h_lo,
        const ushort* __restrict__ swh, const ushort* __restrict__ swl,
        const float* __restrict__ al, const float* __restrict__ ar,
        __half* __restrict__ feat, float* __restrict__ el, float* __restrict__ er, int n) {
    const int lane = threadIdx.x & 63;
    const int w    = threadIdx.x >> 6;
    const int tile = blockIdx.x * 4 + w;
    if (tile * 16 >= n) return;
    const int row0 = tile * 16;
    const int arow = row0 + (lane & 15);
    const ushort* Ah_b = h_hi + (size_t)arow * DIN + ((lane >> 4) * 8);
    const ushort* Al_b = h_lo + (size_t)arow * DIN + ((lane >> 4) * 8);

    f32x4 acc[8];
    #pragma unroll
    for (int ct = 0; ct < 8; ++ct) acc[ct] = (f32x4){0.f, 0.f, 0.f, 0.f};

    #pragma unroll
    for (int ks = 0; ks < 4; ++ks) {
        bf16x8 Ah = *(const bf16x8*)(Ah_b + ks * 32);
        bf16x8 Al = *(const bf16x8*)(Al_b + ks * 32);
        #pragma unroll
        for (int ct = 0; ct < 8; ++ct) {
            const int fi = ks * 8 + ct;
            bf16x8 Bh = *(const bf16x8*)(swh + fi * 512 + lane * 8);
            bf16x8 Bl = *(const bf16x8*)(swl + fi * 512 + lane * 8);
            acc[ct] = __builtin_amdgcn_mfma_f32_16x16x32_bf16(Ah, Bh, acc[ct], 0, 0, 0);
            acc[ct] = __builtin_amdgcn_mfma_f32_16x16x32_bf16(Ah, Bl, acc[ct], 0, 0, 0);
            acc[ct] = __builtin_amdgcn_mfma_f32_16x16x32_bf16(Al, Bh, acc[ct], 0, 0, 0);
        }
    }

    const int m0 = (lane >> 4) * 4;
    const int ncol = lane & 15;
    float elp0[4] = {0,0,0,0}, elp1[4] = {0,0,0,0};
    float erp0[4] = {0,0,0,0}, erp1[4] = {0,0,0,0};
    #pragma unroll
    for (int ct = 0; ct < 8; ++ct) {
        const float a_l = al[ct * 16 + ncol];
        const float a_r = ar[ct * 16 + ncol];
        #pragma unroll
        for (int r = 0; r < 4; ++r) {
            float v = acc[ct][r];
            feat[(size_t)(row0 + m0 + r) * D1 + ct * 16 + ncol] = __float2half(v);
            if (ct < 4) { elp0[r] = fmaf(v, a_l, elp0[r]); erp0[r] = fmaf(v, a_r, erp0[r]); }
            else        { elp1[r] = fmaf(v, a_l, elp1[r]); erp1[r] = fmaf(v, a_r, erp1[r]); }
        }
    }
    #pragma unroll
    for (int o = 1; o < 16; o <<= 1) {
        #pragma unroll
        for (int r = 0; r < 4; ++r) {
            elp0[r] += __shfl_xor(elp0[r], o, 64);
            elp1[r] += __shfl_xor(elp1[r], o, 64);
            erp0[r] += __shfl_xor(erp0[r], o, 64);
            erp1[r] += __shfl_xor(erp1[r], o, 64);
        }
    }
    if (ncol == 0) {
        #pragma unroll
        for (int r = 0; r < 4; ++r) {
            int row = row0 + m0 + r;
            el[row * 2 + 0] = elp0[r]; el[row * 2 + 1] = elp1[r];
            er[row * 2 + 0] = erp0[r]; er[row * 2 + 1] = erp1[r];
        }
    }
}

// ---------------- per-node aggregation ----------------
// Fast path (deg<=64): lane j owns edge j for softmax (register-resident).
// Pass C (R10 lesson: serial readlane loop was issue-bound): 4 edge-groups
// (g=lane>>4) process edges j=4t+g in parallel; lane's feature slice
// fl=lane&15 covers features fl*8..+7 (fl<8 <=> head0). Broadcast of
// (src, a0, a1) via ds_bpermute (per-lane, no LDS/barrier); gathers are
// 16B/lane (wave instruction = 4 edges x 256B = 1KB). Final 2-step
// shfl_xor butterfly (16,32) reduces the 4 group-partials.

__device__ __forceinline__ float leaky(float x) {
    return x > 0.f ? x : NEG_SLOPE * x;
}
__device__ __forceinline__ float bperm_f(int addr, float v) {
    return __uint_as_float(__builtin_amdgcn_ds_bpermute(addr, __float_as_uint(v)));
}

template<bool OUT_BF16>
__global__ __launch_bounds__(256) void k_node_agg(
        const __half* __restrict__ feat, const float* __restrict__ el, const float* __restrict__ er,
        const int* __restrict__ row_off, const int* __restrict__ csr_src,
        const float* __restrict__ bias,
        float* __restrict__ out, ushort* __restrict__ o_hi, ushort* __restrict__ o_lo, int n) {
    const int wave = (blockIdx.x * blockDim.x + threadIdx.x) >> 6;
    const int lane = threadIdx.x & 63;
    if (wave >= n) return;
    const int node = wave;
    const int beg = row_off[node], end = row_off[node + 1];
    const int deg = end - beg;
    const float2 erv = (deg > 0) ? ((const float2*)er)[node] : make_float2(0.f, 0.f);

    if (deg <= 64) {
        // --- softmax: lane j owns edge j ---
        int s_reg = 0;
        float e0 = -INFINITY, e1 = -INFINITY;
        if (lane < deg) {
            s_reg = csr_src[beg + lane];
            float2 elv = ((const float2*)el)[s_reg];
            e0 = leaky(elv.x + erv.x);
            e1 = leaky(elv.y + erv.y);
        }
        float m0 = e0, m1 = e1;
        #pragma unroll
        for (int o = 32; o > 0; o >>= 1) {
            m0 = fmaxf(m0, __shfl_xor(m0, o, 64));
            m1 = fmaxf(m1, __shfl_xor(m1, o, 64));
        }
        float p0 = (lane < deg) ? expf(e0 - m0) : 0.f;
        float p1 = (lane < deg) ? expf(e1 - m1) : 0.f;
        float s0 = p0, s1 = p1;
        #pragma unroll
        for (int o = 32; o > 0; o >>= 1) {
            s0 += __shfl_xor(s0, o, 64);
            s1 += __shfl_xor(s1, o, 64);
        }
        const float a0 = p0 / s0;   // pre-divided alphas (NaN only if deg==0: unused)
        const float a1 = p1 / s1;

        // --- pass C: 4 edge-groups, 16B gathers ---
        const int g  = lane >> 4;
        const int fl = lane & 15;
        float accv[8] = {0,0,0,0,0,0,0,0};
        const int nIt = (deg + 3) >> 2;
        #pragma unroll 2
        for (int t = 0; t < nIt; ++t) {
            const int j = t * 4 + g;
            const int addr = j << 2;
            int   sj  = __builtin_amdgcn_ds_bpermute(addr, s_reg);
            float aj0 = bperm_f(addr, a0);
            float aj1 = bperm_f(addr, a1);
            float ah = (fl < 8) ? aj0 : aj1;
            if (j >= deg) { ah = 0.f; sj = 0; }
            union { uint4 u; __half2 h[4]; } fr;
            fr.u = *(const uint4*)(feat + (size_t)sj * D1 + fl * 8);
            #pragma unroll
            for (int q = 0; q < 4; ++q) {
                float2 f2 = __half22float2(fr.h[q]);
                accv[2 * q]     = fmaf(ah, f2.x, accv[2 * q]);
                accv[2 * q + 1] = fmaf(ah, f2.y, accv[2 * q + 1]);
            }
        }
        // reduce the 4 group-partials (lanes with same fl)
        #pragma unroll
        for (int o = 16; o <= 32; o <<= 1) {
            #pragma unroll
            for (int q = 0; q < 8; ++q) accv[q] += __shfl_xor(accv[q], o, 64);
        }
        // bias + relu + write (lanes 0..15 hold the full row)
        if (lane < 16) {
            const float4 b0v = ((const float4*)(bias + fl * 8))[0];
            const float4 b1v = ((const float4*)(bias + fl * 8))[1];
            float v[8];
            v[0] = fmaxf(accv[0] + b0v.x, 0.f); v[1] = fmaxf(accv[1] + b0v.y, 0.f);
            v[2] = fmaxf(accv[2] + b0v.z, 0.f); v[3] = fmaxf(accv[3] + b0v.w, 0.f);
            v[4] = fmaxf(accv[4] + b1v.x, 0.f); v[5] = fmaxf(accv[5] + b1v.y, 0.f);
            v[6] = fmaxf(accv[6] + b1v.z, 0.f); v[7] = fmaxf(accv[7] + b1v.w, 0.f);
            if (OUT_BF16) {
                uint hb[4], lb[4];
                #pragma unroll
                for (int q = 0; q < 4; ++q) split2(v[2 * q], v[2 * q + 1], hb[q], lb[q]);
                ((uint4*)(o_hi + (size_t)node * D1))[fl] = make_uint4(hb[0], hb[1], hb[2], hb[3]);
                ((uint4*)(o_lo + (size_t)node * D1))[fl] = make_uint4(lb[0], lb[1], lb[2], lb[3]);
            } else {
                float4* op = (float4*)(out + (size_t)node * D1 + fl * 8);
                op[0] = make_float4(v[0], v[1], v[2], v[3]);
                op[1] = make_float4(v[4], v[5], v[6], v[7]);
            }
        }
    } else {
        // --- generic fallback (deg > 64): old layout, lane owns cols {2L,2L+1} ---
        float2 acc = make_float2(0.f, 0.f);
        float m0 = -INFINITY, m1 = -INFINITY;
        for (int j = beg + lane; j < end; j += 64) {
            int s = csr_src[j];
            float2 elv = ((const float2*)el)[s];
            m0 = fmaxf(m0, leaky(elv.x + erv.x));
            m1 = fmaxf(m1, leaky(elv.y + erv.y));
        }
        #pragma unroll
        for (int o = 32; o > 0; o >>= 1) {
            m0 = fmaxf(m0, __shfl_xor(m0, o, 64));
            m1 = fmaxf(m1, __shfl_xor(m1, o, 64));
        }
        float s0 = 0.f, s1 = 0.f;
        for (int j = beg + lane; j < end; j += 64) {
            int s = csr_src[j];
            float2 elv = ((const float2*)el)[s];
            s0 += expf(leaky(elv.x + erv.x) - m0);
            s1 += expf(leaky(elv.y + erv.y) - m1);
        }
        #pragma unroll
        for (int o = 32; o > 0; o >>= 1) {
            s0 += __shfl_xor(s0, o, 64);
            s1 += __shfl_xor(s1, o, 64);
        }
        const float inv0 = 1.f / s0, inv1 = 1.f / s1;
        for (int j = beg; j < end; ++j) {
            int s = csr_src[j];
            float2 elv = ((const float2*)el)[s];
            float av0 = expf(leaky(elv.x + erv.x) - m0) * inv0;
            float av1 = expf(leaky(elv.y + erv.y) - m1) * inv1;
            float ah = (lane < 32) ? av0 : av1;
            __half2 f = ((const __half2*)(feat + (size_t)s * D1))[lane];
            acc.x = fmaf(ah, __low2float(f),  acc.x);
            acc.y = fmaf(ah, __high2float(f), acc.y);
        }
        const float2 b2 = ((const float2*)bias)[lane];
        float o0 = fmaxf(acc.x + b2.x, 0.f);
        float o1 = fmaxf(acc.y + b2.y, 0.f);
        if (OUT_BF16) {
            uint hi, lo;
            split2(o0, o1, hi, lo);
            ((uint*)o_hi)[(size_t)node * (D1 / 2) + lane] = hi;
            ((uint*)o_lo)[(size_t)node * (D1 / 2) + lane] = lo;
        } else {
            ((float2*)(out + (size_t)node * D1))[lane] = make_float2(o0, o1);
        }
    }
}

// ---------------- launch ----------------

extern "C" void kernel_launch(void* const* d_in, const int* in_sizes, int n_in,
                              void* d_out, int out_size, void* d_ws, size_t ws_size,
                              hipStream_t stream) {
    const float* features    = (const float*)d_in[0];
    const int*   labels      = (const int*)  d_in[1];
    const int*   src         = (const int*)  d_in[2];
    const int*   dst         = (const int*)  d_in[3];
    const float* label_embed = (const float*)d_in[4];
    const float* W0  = (const float*)d_in[5];
    const float* al0 = (const float*)d_in[6];
    const float* ar0 = (const float*)d_in[7];
    const float* b0  = (const float*)d_in[8];
    const float* W1  = (const float*)d_in[9];
    const float* al1 = (const float*)d_in[10];
    const float* ar1 = (const float*)d_in[11];
    const float* b1  = (const float*)d_in[12];

    const int n = in_sizes[1];   // NNODES
    const int e = in_sizes[2];   // NEDGES
    const int nb = (n + SCAN_CHUNK - 1) / SCAN_CHUNK;

    size_t off = 0;
    auto carve = [&](size_t bytes) {
        void* p = (char*)d_ws + off;
        off += (bytes + 255) & ~(size_t)255;
        return p;
    };
    __half* feat    = (__half*)carve((size_t)n * D1 * 2);
    float*  el      = (float*) carve((size_t)n * 2 * 4);
    float*  er      = (float*) carve((size_t)n * 2 * 4);
    int*    row_off = (int*)   carve((size_t)(n + 1) * 4);
    int*    cursor  = (int*)   carve((size_t)n * 4);
    int*    csr_src = (int*)   carve((size_t)e * 4);
    int*    bsum    = (int*)   carve((size_t)nb * 4);
    int*    boff    = (int*)   carve((size_t)(nb + 1) * 4);
    ushort* w0h     = (ushort*)carve(32 * 512 * 2);
    ushort* w0l     = (ushort*)carve(32 * 512 * 2);
    ushort* w1h     = (ushort*)carve(32 * 512 * 2);
    ushort* w1l     = (ushort*)carve(32 * 512 * 2);
    ushort* h_hi;
    ushort* h_lo;
    if (off + 2 * (size_t)n * D1 * 2 <= ws_size) {
        h_hi = (ushort*)carve((size_t)n * D1 * 2);
        h_lo = (ushort*)carve((size_t)n * D1 * 2);
    } else {
        h_hi = (ushort*)d_out;
        h_lo = h_hi + (size_t)n * D1;
    }

    const int B = 256;
    // --- CSR build ---
    hipLaunchKernelGGL(k_zero_int,  dim3((n + B - 1) / B), dim3(B), 0, stream, cursor, n);
    hipLaunchKernelGGL(k_count,     dim3((e + B - 1) / B), dim3(B), 0, stream, dst, cursor, e);
    hipLaunchKernelGGL(k_partial,   dim3(nb), dim3(B), 0, stream, cursor, bsum, n);
    hipLaunchKernelGGL(k_scan_excl, dim3(1),  dim3(B), 0, stream, bsum, boff, nb);
    hipLaunchKernelGGL(k_scan_chunk,dim3(nb), dim3(B), 0, stream, cursor, boff, row_off, cursor, n, nb);
    hipLaunchKernelGGL(k_scatter,   dim3((e + B - 1) / B), dim3(B), 0, stream, src, dst, cursor, csr_src, e);

    // --- W pre-swizzle + h0 split ---
    hipLaunchKernelGGL(k_wswz, dim3(8), dim3(B), 0, stream, W0, w0h, w0l);
    hipLaunchKernelGGL(k_wswz, dim3(8), dim3(B), 0, stream, W1, w1h, w1l);
    hipLaunchKernelGGL(k_embed_split, dim3((n * (DIN / 2) + B - 1) / B), dim3(B), 0, stream,
                       features, labels, label_embed, h_hi, h_lo, n);

    const int tiles = (n + 15) / 16;
    const int gemm_grid = (tiles + 3) / 4;
    const int agg_grid  = (n + 3) / 4;

    // --- layer 0 ---
    hipLaunchKernelGGL(k_gemm_mfma, dim3(gemm_grid), dim3(B), 0, stream,
                       h_hi, h_lo, w0h, w0l, al0, ar0, feat, el, er, n);
    hipLaunchKernelGGL((k_node_agg<true>), dim3(agg_grid), dim3(B), 0, stream,
                       feat, el, er, row_off, csr_src, b0,
                       (float*)nullptr, h_hi, h_lo, n);

    // --- layer 1 ---
    hipLaunchKernelGGL(k_gemm_mfma, dim3(gemm_grid), dim3(B), 0, stream,
                       h_hi, h_lo, w1h, w1l, al1, ar1, feat, el, er, n);
    hipLaunchKernelGGL((k_node_agg<false>), dim3(agg_grid), dim3(B), 0, stream,
                       feat, el, er, row_off, csr_src, b1,
                       (float*)d_out, (ushort*)nullptr, (ushort*)nullptr, n);
}

// Round 12
// 228.941 us; speedup vs baseline: 1.8619x; 1.0394x over previous
//
#include <hip/hip_runtime.h>
#include <hip/hip_fp16.h>
#include <math.h>

#define NNODES 50000
#define NEDGES 800000
#define DIN 128
#define D1 128          // HEADS*HID
#define HID 64
#define NEG_SLOPE 0.2f
#define SCAN_CHUNK 1024

typedef __attribute__((ext_vector_type(4))) float f32x4;
typedef __attribute__((ext_vector_type(8))) short bf16x8;

// ---- bf16 split helpers (RNE) ----
__device__ __forceinline__ ushort f2bf(float x) {
    uint u = __float_as_uint(x);
    return (ushort)((u + 0x7fff + ((u >> 16) & 1)) >> 16);
}
__device__ __forceinline__ float bf2f(ushort h) {
    return __uint_as_float(((uint)h) << 16);
}
__device__ __forceinline__ void split2(float x, float y, uint& hi, uint& lo) {
    ushort xh = f2bf(x); ushort xl = f2bf(x - bf2f(xh));
    ushort yh = f2bf(y); ushort yl = f2bf(y - bf2f(yh));
    hi = (uint)xh | ((uint)yh << 16);
    lo = (uint)xl | ((uint)yl << 16);
}

// ---------------- utility ----------------

__global__ void k_zero_int(int* p, int n) {
    int i = blockIdx.x * blockDim.x + threadIdx.x;
    if (i < n) p[i] = 0;
}

// ---------------- CSR build ----------------

__global__ void k_count(const int* __restrict__ dst, int* __restrict__ counts, int e) {
    int i = blockIdx.x * blockDim.x + threadIdx.x;
    if (i < e) atomicAdd(&counts[dst[i]], 1);
}

__global__ __launch_bounds__(256) void k_partial(const int* __restrict__ c,
                                                 int* __restrict__ bsum, int n) {
    __shared__ int wsum[4];
    const int tid = threadIdx.x, lane = tid & 63, w = tid >> 6;
    int base = blockIdx.x * SCAN_CHUNK + tid * 4;
    int v = 0;
    if (base + 3 < n) {
        int4 x = *(const int4*)(c + base);
        v = x.x + x.y + x.z + x.w;
    } else {
        #pragma unroll
        for (int j = 0; j < 4; ++j) if (base + j < n) v += c[base + j];
    }
    #pragma unroll
    for (int o = 32; o > 0; o >>= 1) v += __shfl_xor(v, o, 64);
    if (lane == 0) wsum[w] = v;
    __syncthreads();
    if (tid == 0) bsum[blockIdx.x] = wsum[0] + wsum[1] + wsum[2] + wsum[3];
}

__global__ void k_scan_excl(const int* __restrict__ counts, int* __restrict__ row_off, int n) {
    __shared__ int s_carry;
    __shared__ int s_wsum[4];
    const int tid  = threadIdx.x;
    const int lane = tid & 63;
    const int w    = tid >> 6;
    if (tid == 0) s_carry = 0;
    __syncthreads();
    for (int base = 0; base < n; base += 256) {
        int i = base + tid;
        int orig = (i < n) ? counts[i] : 0;
        int v = orig;
        #pragma unroll
        for (int o = 1; o < 64; o <<= 1) {
            int t = __shfl_up(v, o, 64);
            if (lane >= o) v += t;
        }
        if (lane == 63) s_wsum[w] = v;
        __syncthreads();
        int woff = 0;
        for (int j = 0; j < w; ++j) woff += s_wsum[j];
        int incl = v + woff;
        int carry = s_carry;
        if (i < n) row_off[i] = carry + incl - orig;
        __syncthreads();
        if (tid == 255) s_carry = carry + incl;
        __syncthreads();
    }
    if (tid == 0) row_off[n] = s_carry;
}

__global__ __launch_bounds__(256) void k_scan_chunk(const int* __restrict__ c,
                                                    const int* __restrict__ boff,
                                                    int* __restrict__ row_off,
                                                    int* __restrict__ cursor,
                                                    int n, int nb) {
    __shared__ int wsum[4];
    const int tid = threadIdx.x, lane = tid & 63, w = tid >> 6;
    int base = blockIdx.x * SCAN_CHUNK + tid * 4;
    int v0 = 0, v1 = 0, v2 = 0, v3 = 0;
    if (base + 3 < n) {
        int4 x = *(const int4*)(c + base);
        v0 = x.x; v1 = x.y; v2 = x.z; v3 = x.w;
    } else {
        if (base     < n) v0 = c[base];
        if (base + 1 < n) v1 = c[base + 1];
        if (base + 2 < n) v2 = c[base + 2];
        if (base + 3 < n) v3 = c[base + 3];
    }
    int ts = v0 + v1 + v2 + v3;
    int incl = ts;
    #pragma unroll
    for (int o = 1; o < 64; o <<= 1) {
        int t = __shfl_up(incl, o, 64);
        if (lane >= o) incl += t;
    }
    if (lane == 63) wsum[w] = incl;
    __syncthreads();
    int woff = 0;
    for (int j = 0; j < w; ++j) woff += wsum[j];
    int pre = boff[blockIdx.x] + woff + incl - ts;
    int e0 = pre, e1 = pre + v0, e2 = e1 + v1, e3 = e2 + v2;
    if (base     < n) { row_off[base]     = e0; cursor[base]     = e0; }
    if (base + 1 < n) { row_off[base + 1] = e1; cursor[base + 1] = e1; }
    if (base + 2 < n) { row_off[base + 2] = e2; cursor[base + 2] = e2; }
    if (base + 3 < n) { row_off[base + 3] = e3; cursor[base + 3] = e3; }
    if (blockIdx.x == 0 && tid == 0) row_off[n] = boff[nb];
}

// XCD-sliced scatter (R11 lesson: flat scatter = 800k cross-XCD random 4B
// stores -> 51.8MB HBM write traffic, 52us). Block b: edge chunk b>>3,
// scatters ONLY dsts in slice (b&7). Under round-robin blockIdx->XCD
// dispatch, slice s's csr region (~400KB) + cursor (~25KB) live in one
// XCD's L2 -> stores/atomics L2-absorbed. Perf-only assumption; correct
// under any mapping. Cost: 8x sequential dst reads (~50MB streamed).
__global__ __launch_bounds__(256) void k_scatter8(
        const int* __restrict__ src, const int* __restrict__ dst,
        int* __restrict__ cursor, int* __restrict__ csr_src, int e, int slice_sz) {
    const int s     = blockIdx.x & 7;
    const int chunk = blockIdx.x >> 3;
    const int lo = s * slice_sz;
    const int hi = lo + slice_sz;
    const int base = chunk * 1024 + threadIdx.x * 4;
    if (base >= e) return;
    int4 d;
    if (base + 3 < e) {
        d = *(const int4*)(dst + base);
    } else {
        d.x = dst[base];
        d.y = (base + 1 < e) ? dst[base + 1] : -1;
        d.z = (base + 2 < e) ? dst[base + 2] : -1;
        d.w = (base + 3 < e) ? dst[base + 3] : -1;
    }
    if (d.x >= lo && d.x < hi) { int t = atomicAdd(&cursor[d.x], 1); csr_src[t] = src[base]; }
    if (d.y >= lo && d.y < hi) { int t = atomicAdd(&cursor[d.y], 1); csr_src[t] = src[base + 1]; }
    if (d.z >= lo && d.z < hi) { int t = atomicAdd(&cursor[d.z], 1); csr_src[t] = src[base + 2]; }
    if (d.w >= lo && d.w < hi) { int t = atomicAdd(&cursor[d.w], 1); csr_src[t] = src[base + 3]; }
}

// ---------------- pre-kernels for MFMA gemm ----------------

__global__ void k_embed_split(const float* __restrict__ features, const int* __restrict__ labels,
                              const float* __restrict__ le,
                              ushort* __restrict__ h_hi, ushort* __restrict__ h_lo, int n) {
    int idx = blockIdx.x * blockDim.x + threadIdx.x;   // one float2 pair
    if (idx >= n * (DIN / 2)) return;
    int node = idx >> 6, q = idx & 63;
    float2 f = ((const float2*)features)[idx];
    float2 l = ((const float2*)(le + (size_t)labels[node] * DIN))[q];
    uint hi, lo;
    split2(f.x + l.x, f.y + l.y, hi, lo);
    ((uint*)h_hi)[idx] = hi;
    ((uint*)h_lo)[idx] = lo;
}

// W [128][128] f32 -> pre-swizzled bf16 hi/lo fragments (see R9 notes: only
// row(A)/col(B)=lane&15 must match C/D layout; k-slot order just needs A/B agree).
__global__ void k_wswz(const float* __restrict__ W,
                       ushort* __restrict__ swh, ushort* __restrict__ swl) {
    int t = blockIdx.x * blockDim.x + threadIdx.x;
    if (t >= 32 * 64) return;
    int fi = t >> 6, lane = t & 63;
    int ks = fi >> 3, ct = fi & 7;
    int kb = ks * 32 + ((lane >> 4) * 8);
    int col = ct * 16 + (lane & 15);
    uint h[4], l[4];
    #pragma unroll
    for (int p = 0; p < 4; ++p) {
        float v0 = W[(size_t)(kb + 2 * p) * D1 + col];
        float v1 = W[(size_t)(kb + 2 * p + 1) * D1 + col];
        split2(v0, v1, h[p], l[p]);
    }
    uint4* oh = (uint4*)(swh + fi * 512 + lane * 8);
    uint4* ol = (uint4*)(swl + fi * 512 + lane * 8);
    *oh = make_uint4(h[0], h[1], h[2], h[3]);
    *ol = make_uint4(l[0], l[1], l[2], l[3]);
}

// ---------------- MFMA gemm: feat = h @ W, el/er fused ----------------

__global__ __launch_bounds__(256) void k_gemm_mfma(
        const ushort* __restrict__ h_hi, const ushort* __restrict__ h_lo,
        const ushort* __restrict__ swh, const ushort* __restrict__ swl,
        const float* __restrict__ al, const float* __restrict__ ar,
        __half* __restrict__ feat, float* __restrict__ el, float* __restrict__ er, int n) {
    const int lane = threadIdx.x & 63;
    const int w    = threadIdx.x >> 6;
    const int tile = blockIdx.x * 4 + w;
    if (tile * 16 >= n) return;
    const int row0 = tile * 16;
    const int arow = row0 + (lane & 15);
    const ushort* Ah_b = h_hi + (size_t)arow * DIN + ((lane >> 4) * 8);
    const ushort* Al_b = h_lo + (size_t)arow * DIN + ((lane >> 4) * 8);

    f32x4 acc[8];
    #pragma unroll
    for (int ct = 0; ct < 8; ++ct) acc[ct] = (f32x4){0.f, 0.f, 0.f, 0.f};

    #pragma unroll
    for (int ks = 0; ks < 4; ++ks) {
        bf16x8 Ah = *(const bf16x8*)(Ah_b + ks * 32);
        bf16x8 Al = *(const bf16x8*)(Al_b + ks * 32);
        #pragma unroll
        for (int ct = 0; ct < 8; ++ct) {
            const int fi = ks * 8 + ct;
            bf16x8 Bh = *(const bf16x8*)(swh + fi * 512 + lane * 8);
            bf16x8 Bl = *(const bf16x8*)(swl + fi * 512 + lane * 8);
            acc[ct] = __builtin_amdgcn_mfma_f32_16x16x32_bf16(Ah, Bh, acc[ct], 0, 0, 0);
            acc[ct] = __builtin_amdgcn_mfma_f32_16x16x32_bf16(Ah, Bl, acc[ct], 0, 0, 0);
            acc[ct] = __builtin_amdgcn_mfma_f32_16x16x32_bf16(Al, Bh, acc[ct], 0, 0, 0);
        }
    }

    const int m0 = (lane >> 4) * 4;
    const int ncol = lane & 15;
    float elp0[4] = {0,0,0,0}, elp1[4] = {0,0,0,0};
    float erp0[4] = {0,0,0,0}, erp1[4] = {0,0,0,0};
    #pragma unroll
    for (int ct = 0; ct < 8; ++ct) {
        const float a_l = al[ct * 16 + ncol];
        const float a_r = ar[ct * 16 + ncol];
        #pragma unroll
        for (int r = 0; r < 4; ++r) {
            float v = acc[ct][r];
            feat[(size_t)(row0 + m0 + r) * D1 + ct * 16 + ncol] = __float2half(v);
            if (ct < 4) { elp0[r] = fmaf(v, a_l, elp0[r]); erp0[r] = fmaf(v, a_r, erp0[r]); }
            else        { elp1[r] = fmaf(v, a_l, elp1[r]); erp1[r] = fmaf(v, a_r, erp1[r]); }
        }
    }
    #pragma unroll
    for (int o = 1; o < 16; o <<= 1) {
        #pragma unroll
        for (int r = 0; r < 4; ++r) {
            elp0[r] += __shfl_xor(elp0[r], o, 64);
            elp1[r] += __shfl_xor(elp1[r], o, 64);
            erp0[r] += __shfl_xor(erp0[r], o, 64);
            erp1[r] += __shfl_xor(erp1[r], o, 64);
        }
    }
    if (ncol == 0) {
        #pragma unroll
        for (int r = 0; r < 4; ++r) {
            int row = row0 + m0 + r;
            el[row * 2 + 0] = elp0[r]; el[row * 2 + 1] = elp1[r];
            er[row * 2 + 0] = erp0[r]; er[row * 2 + 1] = erp1[r];
        }
    }
}

// ---------------- per-node aggregation ----------------

__device__ __forceinline__ float leaky(float x) {
    return x > 0.f ? x : NEG_SLOPE * x;
}
__device__ __forceinline__ float bperm_f(int addr, float v) {
    return __uint_as_float(__builtin_amdgcn_ds_bpermute(addr, __float_as_uint(v)));
}

template<bool OUT_BF16>
__global__ __launch_bounds__(256) void k_node_agg(
        const __half* __restrict__ feat, const float* __restrict__ el, const float* __restrict__ er,
        const int* __restrict__ row_off, const int* __restrict__ csr_src,
        const float* __restrict__ bias,
        float* __restrict__ out, ushort* __restrict__ o_hi, ushort* __restrict__ o_lo, int n) {
    const int wave = (blockIdx.x * blockDim.x + threadIdx.x) >> 6;
    const int lane = threadIdx.x & 63;
    if (wave >= n) return;
    const int node = wave;
    const int beg = row_off[node], end = row_off[node + 1];
    const int deg = end - beg;
    const float2 erv = (deg > 0) ? ((const float2*)er)[node] : make_float2(0.f, 0.f);

    if (deg <= 64) {
        int s_reg = 0;
        float e0 = -INFINITY, e1 = -INFINITY;
        if (lane < deg) {
            s_reg = csr_src[beg + lane];
            float2 elv = ((const float2*)el)[s_reg];
            e0 = leaky(elv.x + erv.x);
            e1 = leaky(elv.y + erv.y);
        }
        float m0 = e0, m1 = e1;
        #pragma unroll
        for (int o = 32; o > 0; o >>= 1) {
            m0 = fmaxf(m0, __shfl_xor(m0, o, 64));
            m1 = fmaxf(m1, __shfl_xor(m1, o, 64));
        }
        float p0 = (lane < deg) ? expf(e0 - m0) : 0.f;
        float p1 = (lane < deg) ? expf(e1 - m1) : 0.f;
        float s0 = p0, s1 = p1;
        #pragma unroll
        for (int o = 32; o > 0; o >>= 1) {
            s0 += __shfl_xor(s0, o, 64);
            s1 += __shfl_xor(s1, o, 64);
        }
        const float a0 = p0 / s0;
        const float a1 = p1 / s1;

        const int g  = lane >> 4;
        const int fl = lane & 15;
        float accv[8] = {0,0,0,0,0,0,0,0};
        const int nIt = (deg + 3) >> 2;
        #pragma unroll 2
        for (int t = 0; t < nIt; ++t) {
            const int j = t * 4 + g;
            const int addr = j << 2;
            int   sj  = __builtin_amdgcn_ds_bpermute(addr, s_reg);
            float aj0 = bperm_f(addr, a0);
            float aj1 = bperm_f(addr, a1);
            float ah = (fl < 8) ? aj0 : aj1;
            if (j >= deg) { ah = 0.f; sj = 0; }
            union { uint4 u; __half2 h[4]; } fr;
            fr.u = *(const uint4*)(feat + (size_t)sj * D1 + fl * 8);
            #pragma unroll
            for (int q = 0; q < 4; ++q) {
                float2 f2 = __half22float2(fr.h[q]);
                accv[2 * q]     = fmaf(ah, f2.x, accv[2 * q]);
                accv[2 * q + 1] = fmaf(ah, f2.y, accv[2 * q + 1]);
            }
        }
        #pragma unroll
        for (int o = 16; o <= 32; o <<= 1) {
            #pragma unroll
            for (int q = 0; q < 8; ++q) accv[q] += __shfl_xor(accv[q], o, 64);
        }
        if (lane < 16) {
            const float4 b0v = ((const float4*)(bias + fl * 8))[0];
            const float4 b1v = ((const float4*)(bias + fl * 8))[1];
            float v[8];
            v[0] = fmaxf(accv[0] + b0v.x, 0.f); v[1] = fmaxf(accv[1] + b0v.y, 0.f);
            v[2] = fmaxf(accv[2] + b0v.z, 0.f); v[3] = fmaxf(accv[3] + b0v.w, 0.f);
            v[4] = fmaxf(accv[4] + b1v.x, 0.f); v[5] = fmaxf(accv[5] + b1v.y, 0.f);
            v[6] = fmaxf(accv[6] + b1v.z, 0.f); v[7] = fmaxf(accv[7] + b1v.w, 0.f);
            if (OUT_BF16) {
                uint hb[4], lb[4];
                #pragma unroll
                for (int q = 0; q < 4; ++q) split2(v[2 * q], v[2 * q + 1], hb[q], lb[q]);
                ((uint4*)(o_hi + (size_t)node * D1))[fl] = make_uint4(hb[0], hb[1], hb[2], hb[3]);
                ((uint4*)(o_lo + (size_t)node * D1))[fl] = make_uint4(lb[0], lb[1], lb[2], lb[3]);
            } else {
                float4* op = (float4*)(out + (size_t)node * D1 + fl * 8);
                op[0] = make_float4(v[0], v[1], v[2], v[3]);
                op[1] = make_float4(v[4], v[5], v[6], v[7]);
            }
        }
    } else {
        float2 acc = make_float2(0.f, 0.f);
        float m0 = -INFINITY, m1 = -INFINITY;
        for (int j = beg + lane; j < end; j += 64) {
            int s = csr_src[j];
            float2 elv = ((const float2*)el)[s];
            m0 = fmaxf(m0, leaky(elv.x + erv.x));
            m1 = fmaxf(m1, leaky(elv.y + erv.y));
        }
        #pragma unroll
        for (int o = 32; o > 0; o >>= 1) {
            m0 = fmaxf(m0, __shfl_xor(m0, o, 64));
            m1 = fmaxf(m1, __shfl_xor(m1, o, 64));
        }
        float s0 = 0.f, s1 = 0.f;
        for (int j = beg + lane; j < end; j += 64) {
            int s = csr_src[j];
            float2 elv = ((const float2*)el)[s];
            s0 += expf(leaky(elv.x + erv.x) - m0);
            s1 += expf(leaky(elv.y + erv.y) - m1);
        }
        #pragma unroll
        for (int o = 32; o > 0; o >>= 1) {
            s0 += __shfl_xor(s0, o, 64);
            s1 += __shfl_xor(s1, o, 64);
        }
        const float inv0 = 1.f / s0, inv1 = 1.f / s1;
        for (int j = beg; j < end; ++j) {
            int s = csr_src[j];
            float2 elv = ((const float2*)el)[s];
            float av0 = expf(leaky(elv.x + erv.x) - m0) * inv0;
            float av1 = expf(leaky(elv.y + erv.y) - m1) * inv1;
            float ah = (lane < 32) ? av0 : av1;
            __half2 f = ((const __half2*)(feat + (size_t)s * D1))[lane];
            acc.x = fmaf(ah, __low2float(f),  acc.x);
            acc.y = fmaf(ah, __high2float(f), acc.y);
        }
        const float2 b2 = ((const float2*)bias)[lane];
        float o0 = fmaxf(acc.x + b2.x, 0.f);
        float o1 = fmaxf(acc.y + b2.y, 0.f);
        if (OUT_BF16) {
            uint hi, lo;
            split2(o0, o1, hi, lo);
            ((uint*)o_hi)[(size_t)node * (D1 / 2) + lane] = hi;
            ((uint*)o_lo)[(size_t)node * (D1 / 2) + lane] = lo;
        } else {
            ((float2*)(out + (size_t)node * D1))[lane] = make_float2(o0, o1);
        }
    }
}

// ---------------- launch ----------------

extern "C" void kernel_launch(void* const* d_in, const int* in_sizes, int n_in,
                              void* d_out, int out_size, void* d_ws, size_t ws_size,
                              hipStream_t stream) {
    const float* features    = (const float*)d_in[0];
    const int*   labels      = (const int*)  d_in[1];
    const int*   src         = (const int*)  d_in[2];
    const int*   dst         = (const int*)  d_in[3];
    const float* label_embed = (const float*)d_in[4];
    const float* W0  = (const float*)d_in[5];
    const float* al0 = (const float*)d_in[6];
    const float* ar0 = (const float*)d_in[7];
    const float* b0  = (const float*)d_in[8];
    const float* W1  = (const float*)d_in[9];
    const float* al1 = (const float*)d_in[10];
    const float* ar1 = (const float*)d_in[11];
    const float* b1  = (const float*)d_in[12];

    const int n = in_sizes[1];   // NNODES
    const int e = in_sizes[2];   // NEDGES
    const int nb = (n + SCAN_CHUNK - 1) / SCAN_CHUNK;

    size_t off = 0;
    auto carve = [&](size_t bytes) {
        void* p = (char*)d_ws + off;
        off += (bytes + 255) & ~(size_t)255;
        return p;
    };
    __half* feat    = (__half*)carve((size_t)n * D1 * 2);
    float*  el      = (float*) carve((size_t)n * 2 * 4);
    float*  er      = (float*) carve((size_t)n * 2 * 4);
    int*    row_off = (int*)   carve((size_t)(n + 1) * 4);
    int*    cursor  = (int*)   carve((size_t)n * 4);
    int*    csr_src = (int*)   carve((size_t)e * 4);
    int*    bsum    = (int*)   carve((size_t)nb * 4);
    int*    boff    = (int*)   carve((size_t)(nb + 1) * 4);
    ushort* w0h     = (ushort*)carve(32 * 512 * 2);
    ushort* w0l     = (ushort*)carve(32 * 512 * 2);
    ushort* w1h     = (ushort*)carve(32 * 512 * 2);
    ushort* w1l     = (ushort*)carve(32 * 512 * 2);
    ushort* h_hi;
    ushort* h_lo;
    if (off + 2 * (size_t)n * D1 * 2 <= ws_size) {
        h_hi = (ushort*)carve((size_t)n * D1 * 2);
        h_lo = (ushort*)carve((size_t)n * D1 * 2);
    } else {
        h_hi = (ushort*)d_out;
        h_lo = h_hi + (size_t)n * D1;
    }

    const int B = 256;
    // --- CSR build ---
    hipLaunchKernelGGL(k_zero_int,  dim3((n + B - 1) / B), dim3(B), 0, stream, cursor, n);
    hipLaunchKernelGGL(k_count,     dim3((e + B - 1) / B), dim3(B), 0, stream, dst, cursor, e);
    hipLaunchKernelGGL(k_partial,   dim3(nb), dim3(B), 0, stream, cursor, bsum, n);
    hipLaunchKernelGGL(k_scan_excl, dim3(1),  dim3(B), 0, stream, bsum, boff, nb);
    hipLaunchKernelGGL(k_scan_chunk,dim3(nb), dim3(B), 0, stream, cursor, boff, row_off, cursor, n, nb);
    {
        const int slice_sz = (n + 7) / 8;
        const int chunks = (e + 1023) / 1024;
        hipLaunchKernelGGL(k_scatter8, dim3(chunks * 8), dim3(B), 0, stream,
                           src, dst, cursor, csr_src, e, slice_sz);
    }

    // --- W pre-swizzle + h0 split ---
    hipLaunchKernelGGL(k_wswz, dim3(8), dim3(B), 0, stream, W0, w0h, w0l);
    hipLaunchKernelGGL(k_wswz, dim3(8), dim3(B), 0, stream, W1, w1h, w1l);
    hipLaunchKernelGGL(k_embed_split, dim3((n * (DIN / 2) + B - 1) / B), dim3(B), 0, stream,
                       features, labels, label_embed, h_hi, h_lo, n);

    const int tiles = (n + 15) / 16;
    const int gemm_grid = (tiles + 3) / 4;
    const int agg_grid  = (n + 3) / 4;

    // --- layer 0 ---
    hipLaunchKernelGGL(k_gemm_mfma, dim3(gemm_grid), dim3(B), 0, stream,
                       h_hi, h_lo, w0h, w0l, al0, ar0, feat, el, er, n);
    hipLaunchKernelGGL((k_node_agg<true>), dim3(agg_grid), dim3(B), 0, stream,
                       feat, el, er, row_off, csr_src, b0,
                       (float*)nullptr, h_hi, h_lo, n);

    // --- layer 1 ---
    hipLaunchKernelGGL(k_gemm_mfma, dim3(gemm_grid), dim3(B), 0, stream,
                       h_hi, h_lo, w1h, w1l, al1, ar1, feat, el, er, n);
    hipLaunchKernelGGL((k_node_agg<false>), dim3(agg_grid), dim3(B), 0, stream,
                       feat, el, er, row_off, csr_src, b1,
                       (float*)d_out, (ushort*)nullptr, (ushort*)nullptr, n);
}